// Round 10
// baseline (387.684 us; speedup 1.0000x reference)
//
#include <hip/hip_runtime.h>
#include <cstdint>
#include <cstddef>

#define S_LEN 2048
#define DM    4096
#define NH    32
#define NKV   8
#define HDIM  128
#define EQ    4096   // NH*HDIM
#define EKV   1024   // NKV*HDIM
#define SC_LOG2E 0.1275325477889277f   // (1/sqrt(128)) * log2(e)

typedef unsigned short u16;
typedef short bf16x8 __attribute__((ext_vector_type(8)));
typedef float f32x4  __attribute__((ext_vector_type(4)));

__device__ __forceinline__ u16 f2bf(float f) {
  union { float f; unsigned u; } v; v.f = f;
  unsigned r = v.u + 0x7FFFu + ((v.u >> 16) & 1u);
  return (u16)(r >> 16);
}
__device__ __forceinline__ float bf2f(u16 b) {
  union { unsigned u; float f; } v; v.u = ((unsigned)b) << 16;
  return v.f;
}
// HW packed fp32->bf16 RNE (ties-even, same as f2bf); a -> low 16, b -> high 16
__device__ __forceinline__ unsigned cvt2bf(float a, float b) {
  unsigned r;
  asm("v_cvt_pk_bf16_f32 %0, %1, %2" : "=v"(r) : "v"(a), "v"(b));
  return r;
}
__device__ __forceinline__ void glds16(const void* g, void* l) {
  __builtin_amdgcn_global_load_lds((const __attribute__((address_space(1))) void*)g,
                                   (__attribute__((address_space(3))) void*)l, 16, 0, 0);
}

// ---------------------------------------------------------------- cast fp32->bf16
__global__ void cast_all(const float* __restrict__ x, const float* __restrict__ wq,
                         const float* __restrict__ wk, const float* __restrict__ wv,
                         const float* __restrict__ wo,
                         u16* __restrict__ xb, u16* __restrict__ wqb,
                         u16* __restrict__ wkb, u16* __restrict__ wvb,
                         u16* __restrict__ wob) {
  const size_t stride = (size_t)gridDim.x * blockDim.x;
  for (size_t u = (size_t)blockIdx.x * blockDim.x + threadIdx.x; u < 12582912u; u += stride) {
    const float* in; u16* outp; size_t i;
    if (u < 2097152u)      { in = x;  outp = xb;  i = u; }
    else if (u < 6291456u) { in = wq; outp = wqb; i = u - 2097152u; }
    else if (u < 7340032u) { in = wk; outp = wkb; i = u - 6291456u; }
    else if (u < 8388608u) { in = wv; outp = wvb; i = u - 7340032u; }
    else                   { in = wo; outp = wob; i = u - 8388608u; }
    float4 f = ((const float4*)in)[i];
    ushort4 b;
    b.x = f2bf(f.x); b.y = f2bf(f.y); b.z = f2bf(f.z); b.w = f2bf(f.w);
    ((ushort4*)outp)[i] = b;
  }
}

// ---------------------------------------------------------------- 2-phase GEMM, BM=128, BN=64*NF
// (R8 configuration verbatim — proven 104/70 us, MfmaUtil 44%, 0 conflicts.
// R9's fp32-reg-staged B regressed to 27% — glds from bf16 weights is the keeper.)
template<int UN>
__device__ __forceinline__ void stage_t(const u16* __restrict__ g, int ldg, int k0,
                                        u16* ldsp, int t) {
  const int wb = t & ~63;
#pragma unroll
  for (int j = 0; j < UN / 256; ++j) {
    const int U = j * 256 + t;
    const int row = U >> 3, u = U & 7;
    const int uu = u ^ (row & 7);
    glds16(g + (size_t)row * ldg + k0 + uu * 8, ldsp + (size_t)(j * 256 + wb) * 8);
  }
}

template<int NF, bool QKV3>
__global__ __launch_bounds__(256, 2)
void gemm2p(const u16* __restrict__ A, const u16* __restrict__ B,
            void* __restrict__ Cq, u16* __restrict__ Ck, u16* __restrict__ Cv,
            int K) {
  constexpr int BN = 64 * NF;
  constexpr int AT = 128 * 64;        // u16 per A tile (8192)
  constexpr int BT = BN * 64;         // u16 per B tile
  __shared__ u16 lds[2 * (AT + BT)];  // A0 @0, A1 @AT, B0 @2*AT, B1 @2*AT+BT
  const int t = threadIdx.x;
  const int l = t & 63, lr = l & 15, lg = l >> 4;
  const int wid = t >> 6, wm = wid >> 1, wn = wid & 1;
  const int m0 = blockIdx.y * 128, n0 = blockIdx.x * BN;
  const int KT = K >> 6;

  const u16* Ab = A + (size_t)m0 * K;
  const u16* Bb = B + (size_t)n0 * K;

  f32x4 acc[4][2 * NF] = {};

  stage_t<1024>(Ab, K, 0, &lds[0], t);
  stage_t<BT / 8>(Bb, K, 0, &lds[2 * AT], t);
  __syncthreads();

  int cur = 0;
#pragma unroll 1
  for (int tau = 0; tau < KT; ++tau) {
    const int kn = (tau + 1 < KT ? tau + 1 : KT - 1) * 64;
    stage_t<1024>(Ab, K, kn, &lds[(cur ^ 1) * AT], t);
    stage_t<BT / 8>(Bb, K, kn, &lds[2 * AT + (cur ^ 1) * BT], t);

    const int aBase = cur * AT;
    const int bBase = 2 * AT + cur * BT;

    bf16x8 af[4][2];
#pragma unroll
    for (int mf = 0; mf < 4; ++mf)
#pragma unroll
      for (int kk = 0; kk < 2; ++kk) {
        const int row = wm * 64 + mf * 16 + lr;
        const int uu = ((kk * 4 + lg) ^ (row & 7)) * 8;
        af[mf][kk] = *(const bf16x8*)&lds[aBase + row * 64 + uu];
      }

#pragma unroll
    for (int n = 0; n < 2 * NF; ++n) {
      const int brow = wn * (32 * NF) + n * 16 + lr;
      const int u0 = ((0 * 4 + lg) ^ (brow & 7)) * 8;
      const int u1 = ((1 * 4 + lg) ^ (brow & 7)) * 8;
      bf16x8 b0 = *(const bf16x8*)&lds[bBase + brow * 64 + u0];
      bf16x8 b1 = *(const bf16x8*)&lds[bBase + brow * 64 + u1];
#pragma unroll
      for (int mf = 0; mf < 4; ++mf) {
        acc[mf][n] = __builtin_amdgcn_mfma_f32_16x16x32_bf16(af[mf][0], b0, acc[mf][n], 0, 0, 0);
        acc[mf][n] = __builtin_amdgcn_mfma_f32_16x16x32_bf16(af[mf][1], b1, acc[mf][n], 0, 0, 0);
      }
    }
    __syncthreads();
    cur ^= 1;
  }

  // epilogue; fragment cols are 16-aligned so QKV routing is per-fragment
#pragma unroll
  for (int mf = 0; mf < 4; ++mf) {
    const int row = m0 + wm * 64 + mf * 16 + lg * 4;
#pragma unroll
    for (int n = 0; n < 2 * NF; ++n) {
      const int gc = n0 + wn * (32 * NF) + n * 16 + lr;
#pragma unroll
      for (int r = 0; r < 4; ++r) {
        if constexpr (QKV3) {
          if (gc < 4096)
            ((u16*)Cq)[(size_t)(row + r) * 4096 + gc] = f2bf(acc[mf][n][r]);
          else if (gc < 5120)
            Ck[(size_t)(row + r) * 1024 + (gc - 4096)] = f2bf(acc[mf][n][r]);
          else
            Cv[(size_t)(row + r) * 1024 + (gc - 5120)] = f2bf(acc[mf][n][r]);
        } else {
          ((float*)Cq)[(size_t)(row + r) * 4096 + gc] = acc[mf][n][r];
        }
      }
    }
  }
}

// ---------------------------------------------------------------- RoPE (q then k)
__global__ void rope_all(u16* __restrict__ qd, u16* __restrict__ kd,
                         const float* __restrict__ cosb, const float* __restrict__ sinb,
                         const int* __restrict__ sidx) {
  const int u = blockIdx.x * blockDim.x + threadIdx.x;
  u16* base; int s, b;
  if (u < 1048576) {
    base = qd + (size_t)u * 8;
    s = u >> 9;
    b = u & 15;
  } else if (u < 1310720) {
    const int u2 = u - 1048576;
    base = kd + (size_t)u2 * 8;
    s = u2 >> 7;
    b = u2 & 15;
  } else return;
  const int pos = sidx[s];
  const float4 c  = *(const float4*)&cosb[pos * 64 + b * 4];
  const float4 sn = *(const float4*)&sinb[pos * 64 + b * 4];
  uint4 raw = *(uint4*)base;
  u16* pe = (u16*)&raw;
  const float cc[4] = {c.x, c.y, c.z, c.w};
  const float ss[4] = {sn.x, sn.y, sn.z, sn.w};
#pragma unroll
  for (int j = 0; j < 4; ++j) {
    const float xr = bf2f(pe[2 * j]), xi = bf2f(pe[2 * j + 1]);
    pe[2 * j]     = f2bf(xr * cc[j] - xi * ss[j]);
    pe[2 * j + 1] = f2bf(xr * ss[j] + xi * cc[j]);
  }
  *(uint4*)base = raw;
}

// ---------------------------------------------------------------- V transpose
__global__ void transpose_v(const u16* __restrict__ v, u16* __restrict__ vt) {
  __shared__ u16 tile[32][33];
  const int tx = threadIdx.x, ty = threadIdx.y;
  const int c0 = blockIdx.x * 32, s0 = blockIdx.y * 32;
#pragma unroll
  for (int j = 0; j < 32; j += 8)
    tile[ty + j][tx] = v[(size_t)(s0 + ty + j) * EKV + c0 + tx];
  __syncthreads();
#pragma unroll
  for (int j = 0; j < 32; j += 8)
    vt[(size_t)(c0 + ty + j) * S_LEN + s0 + tx] = tile[tx][ty + j];
}

// ---------------------------------------------------------------- flash attention
// Merged causal pair (p, 31-p), one KV sweep. NEW: swapped QK^T — compute
// mfma(K, Q) so D has q = lane&15 (each lane owns ONE q-row's 16 scores,
// kv = n*16 + lg*4 + r). Row max/sum become in-register + 2 shfl_xor (vs 4x8
// shfl); P is k-contiguous per lane -> cvt_pk + 4x ds_write_b64 (vs 16 scalar
// writes). K-fragment reads and PV loop are unchanged (A/B frags share the
// same lane layout). sf/lrun live at q=lr and are redistributed to the
// PV-output layout (q=lg*4+r) via 4x __shfl. LDS ops/step: ~82 -> ~46.
#define ATTN_STAGE(TK, BUF) { \
  const int kv0s = (TK) * 64; \
  _Pragma("unroll") \
  for (int hh = 0; hh < 4; ++hh) { \
    const int f = hh * 256 + t; \
    { const int row = f >> 4, uu = f & 15, us = uu ^ (row & 7); \
      glds16(&k[(size_t)(kv0s + row) * EKV + kvh * HDIM + us * 8], &lK[BUF][(hh * 256 + wb) * 8]); } \
    { const int row = f >> 3, uu = f & 7, us = uu ^ (row & 7); \
      glds16(&vt[(size_t)(kvh * HDIM + row) * S_LEN + kv0s + us * 8], &lV[BUF][(hh * 256 + wb) * 8]); } \
  } }

// swapped-layout softmax + P->LDS (vectorized) + PV accumulate
#define SMPV_SW(SC, O, MR, LR, Q0) { \
  _Pragma("unroll") \
  for (int n = 0; n < 4; ++n) { \
    _Pragma("unroll") \
    for (int r = 0; r < 4; ++r) { \
      const int kvc = kv0 + n * 16 + lg * 4 + r; \
      const int qr = (Q0) + lr; \
      const float vv = SC[n][r] * SC_LOG2E; \
      SC[n][r] = (kvc > qr) ? -1e30f : vv; \
    } \
  } \
  float vmx = SC[0][0]; \
  _Pragma("unroll") \
  for (int n = 0; n < 4; ++n) \
    _Pragma("unroll") \
    for (int r = 0; r < 4; ++r) vmx = fmaxf(vmx, SC[n][r]); \
  vmx = fmaxf(vmx, __shfl_xor(vmx, 16)); \
  vmx = fmaxf(vmx, __shfl_xor(vmx, 32)); \
  const float mn = fmaxf(MR, vmx); \
  const float sf = __builtin_amdgcn_exp2f(MR - mn); \
  MR = mn; \
  float rs = 0.f; \
  _Pragma("unroll") \
  for (int n = 0; n < 4; ++n) \
    _Pragma("unroll") \
    for (int r = 0; r < 4; ++r) { \
      const float pv = __builtin_amdgcn_exp2f(SC[n][r] - mn); \
      SC[n][r] = pv; \
      rs += pv; \
    } \
  rs += __shfl_xor(rs, 16); \
  rs += __shfl_xor(rs, 32); \
  LR = LR * sf + rs; \
  { \
    const float s0 = __shfl(sf, lg * 4 + 0); \
    const float s1 = __shfl(sf, lg * 4 + 1); \
    const float s2 = __shfl(sf, lg * 4 + 2); \
    const float s3 = __shfl(sf, lg * 4 + 3); \
    _Pragma("unroll") \
    for (int nh = 0; nh < 8; ++nh) { \
      O[nh][0] *= s0; O[nh][1] *= s1; O[nh][2] *= s2; O[nh][3] *= s3; \
    } \
  } \
  _Pragma("unroll") \
  for (int n = 0; n < 4; ++n) { \
    uint2 wpk; \
    wpk.x = cvt2bf(SC[n][0], SC[n][1]); \
    wpk.y = cvt2bf(SC[n][2], SC[n][3]); \
    *(uint2*)&lPw[lr * 72 + n * 16 + lg * 4] = wpk; \
  } \
  _Pragma("unroll") \
  for (int kc2 = 0; kc2 < 2; ++kc2) { \
    bf16x8 pa = *(const bf16x8*)&lPw[lr * 72 + kc2 * 32 + lg * 8]; \
    _Pragma("unroll") \
    for (int nh = 0; nh < 8; ++nh) { \
      const int row = nh * 16 + lr; \
      const int us = (kc2 * 4 + lg) ^ (row & 7); \
      bf16x8 bv = *(const bf16x8*)&lVc[row * 64 + us * 8]; \
      O[nh] = __builtin_amdgcn_mfma_f32_16x16x32_bf16(pa, bv, O[nh], 0, 0, 0); \
    } \
  } }

__global__ __launch_bounds__(256, 2)
void attn_fwd(const u16* __restrict__ q, const u16* __restrict__ k,
              const u16* __restrict__ vt, u16* __restrict__ ao) {
  __shared__ u16 lK[2][64 * 128];
  __shared__ u16 lV[2][128 * 64];
  __shared__ u16 lP[4 * 16 * 72];
  const int t = threadIdx.x, w = t >> 6, l = t & 63;
  const int lr = l & 15, lg = l >> 4;
  const int wb = t & ~63;
  const int p = blockIdx.x, h = blockIdx.y;
  const int kvh = h >> 2;
  u16* lPw = &lP[w * (16 * 72)];

  const int q0A = p * 64 + w * 16;
  const int q0B = (31 - p) * 64 + w * 16;
  const int nt = 32 - p;

  bf16x8 qaA[4], qaB[4];
#pragma unroll
  for (int kc = 0; kc < 4; ++kc) {
    qaA[kc] = *(const bf16x8*)&q[(size_t)(q0A + lr) * EQ + h * HDIM + kc * 32 + lg * 8];
    qaB[kc] = *(const bf16x8*)&q[(size_t)(q0B + lr) * EQ + h * HDIM + kc * 32 + lg * 8];
  }

  f32x4 oA[8] = {}, oB[8] = {};
  float mA = -1e30f, lA = 0.f, mB = -1e30f, lB = 0.f;

  int cur = 0;
  ATTN_STAGE(0, 0);
  __syncthreads();

#pragma unroll 1
  for (int tk = 0; tk < nt; ++tk) {
    const int kv0 = tk * 64;
    if (tk + 1 < nt) ATTN_STAGE(tk + 1, cur ^ 1);
    const u16* lKc = lK[cur];
    const u16* lVc = lV[cur];

    if (tk <= p) {
      // fused dual QK^T (swapped operands): each bk read feeds both tiles
      f32x4 scB[4] = {}, scA[4] = {};
#pragma unroll
      for (int n = 0; n < 4; ++n) {
#pragma unroll
        for (int kc = 0; kc < 4; ++kc) {
          const int row = n * 16 + lr;
          const int us = (kc * 4 + lg) ^ (row & 7);
          bf16x8 bk = *(const bf16x8*)&lKc[row * 128 + us * 8];
          scB[n] = __builtin_amdgcn_mfma_f32_16x16x32_bf16(bk, qaB[kc], scB[n], 0, 0, 0);
          scA[n] = __builtin_amdgcn_mfma_f32_16x16x32_bf16(bk, qaA[kc], scA[n], 0, 0, 0);
        }
      }
      SMPV_SW(scB, oB, mB, lB, q0B);
      SMPV_SW(scA, oA, mA, lA, q0A);
    } else {
      f32x4 scB[4] = {};
#pragma unroll
      for (int n = 0; n < 4; ++n) {
#pragma unroll
        for (int kc = 0; kc < 4; ++kc) {
          const int row = n * 16 + lr;
          const int us = (kc * 4 + lg) ^ (row & 7);
          bf16x8 bk = *(const bf16x8*)&lKc[row * 128 + us * 8];
          scB[n] = __builtin_amdgcn_mfma_f32_16x16x32_bf16(bk, qaB[kc], scB[n], 0, 0, 0);
        }
      }
      SMPV_SW(scB, oB, mB, lB, q0B);
    }
    __syncthreads();
    cur ^= 1;
  }

  // lrun lives at q=lr; redistribute to the PV-output layout q=lg*4+r
  {
    const float lA0 = __shfl(lA, lg * 4 + 0), lA1 = __shfl(lA, lg * 4 + 1);
    const float lA2 = __shfl(lA, lg * 4 + 2), lA3 = __shfl(lA, lg * 4 + 3);
    const float lB0 = __shfl(lB, lg * 4 + 0), lB1 = __shfl(lB, lg * 4 + 1);
    const float lB2 = __shfl(lB, lg * 4 + 2), lB3 = __shfl(lB, lg * 4 + 3);
    const float rlA[4] = {lA0, lA1, lA2, lA3};
    const float rlB[4] = {lB0, lB1, lB2, lB3};
#pragma unroll
    for (int nh = 0; nh < 8; ++nh)
#pragma unroll
      for (int r = 0; r < 4; ++r) {
        const int col = h * HDIM + nh * 16 + lr;
        ao[(size_t)(q0A + lg * 4 + r) * EQ + col] = f2bf(oA[nh][r] / rlA[r]);
        ao[(size_t)(q0B + lg * 4 + r) * EQ + col] = f2bf(oB[nh][r] / rlB[r]);
      }
  }
}

// ---------------------------------------------------------------- launch
extern "C" void kernel_launch(void* const* d_in, const int* in_sizes, int n_in,
                              void* d_out, int out_size, void* d_ws, size_t ws_size,
                              hipStream_t stream) {
  (void)in_sizes; (void)n_in; (void)out_size; (void)ws_size;
  const float* x    = (const float*)d_in[0];
  const float* wq   = (const float*)d_in[1];
  const float* wk   = (const float*)d_in[2];
  const float* wv   = (const float*)d_in[3];
  const float* wo   = (const float*)d_in[4];
  const float* cosb = (const float*)d_in[7];
  const float* sinb = (const float*)d_in[8];
  const int*   sidx = (const int*)d_in[10];
  float* out = (float*)d_out;

  // workspace layout; wqb/wkb/wvb are contiguous so B_qkv = [wq;wk;wv]
  u16* ws  = (u16*)d_ws;
  u16* xb  = ws;                                  // 2048*4096
  u16* wqb = xb  + (size_t)S_LEN * DM;            // 4096*4096
  u16* wkb = wqb + (size_t)EQ * DM;               // 1024*4096
  u16* wvb = wkb + (size_t)EKV * DM;              // 1024*4096
  u16* wob = wvb + (size_t)EKV * DM;              // 4096*4096
  u16* qb  = wob + (size_t)DM * EQ;               // 2048*4096
  u16* kb  = qb  + (size_t)S_LEN * EQ;            // 2048*1024
  u16* vb  = kb  + (size_t)S_LEN * EKV;           // 2048*1024
  u16* vtb = vb  + (size_t)S_LEN * EKV;           // 1024*2048
  u16* aob = vtb + (size_t)S_LEN * EKV;           // 2048*4096

  cast_all<<<2048, 256, 0, stream>>>(x, wq, wk, wv, wo, xb, wqb, wkb, wvb, wob);
  // fused QKV projection: B = [wq;wk;wv] (6144 x 4096), BM=128/BN=192 -> 32x16 = 512 blocks (2/CU)
  gemm2p<3, true><<<dim3(32, 16), 256, 0, stream>>>(xb, wqb, qb, kb, vb, DM);
  rope_all<<<5120, 256, 0, stream>>>(qb, kb, cosb, sinb, sidx);
  transpose_v<<<dim3(EKV / 32, S_LEN / 32), dim3(32, 8), 0, stream>>>(vb, vtb);
  attn_fwd<<<dim3(16, NH), 256, 0, stream>>>(qb, kb, vtb, aob);
  // O projection: BM=128/BN=128 -> 32x16 = 512 blocks (2/CU)
  gemm2p<2, false><<<dim3(32, 16), 256, 0, stream>>>(aob, wob, out, nullptr, nullptr, EQ);
}

// Round 11
// 361.197 us; speedup vs baseline: 1.0733x; 1.0733x over previous
//
#include <hip/hip_runtime.h>
#include <cstdint>
#include <cstddef>

#define S_LEN 2048
#define DM    4096
#define NH    32
#define NKV   8
#define HDIM  128
#define EQ    4096   // NH*HDIM
#define EKV   1024   // NKV*HDIM
#define SC_LOG2E 0.1275325477889277f   // (1/sqrt(128)) * log2(e)

typedef unsigned short u16;
typedef short bf16x8 __attribute__((ext_vector_type(8)));
typedef float f32x4  __attribute__((ext_vector_type(4)));

__device__ __forceinline__ u16 f2bf(float f) {
  union { float f; unsigned u; } v; v.f = f;
  unsigned r = v.u + 0x7FFFu + ((v.u >> 16) & 1u);
  return (u16)(r >> 16);
}
__device__ __forceinline__ float bf2f(u16 b) {
  union { unsigned u; float f; } v; v.u = ((unsigned)b) << 16;
  return v.f;
}
__device__ __forceinline__ void glds16(const void* g, void* l) {
  __builtin_amdgcn_global_load_lds((const __attribute__((address_space(1))) void*)g,
                                   (__attribute__((address_space(3))) void*)l, 16, 0, 0);
}

// ---------------------------------------------------------------- cast fp32->bf16
__global__ void cast_all(const float* __restrict__ x, const float* __restrict__ wq,
                         const float* __restrict__ wk, const float* __restrict__ wv,
                         const float* __restrict__ wo,
                         u16* __restrict__ xb, u16* __restrict__ wqb,
                         u16* __restrict__ wkb, u16* __restrict__ wvb,
                         u16* __restrict__ wob) {
  const size_t stride = (size_t)gridDim.x * blockDim.x;
  for (size_t u = (size_t)blockIdx.x * blockDim.x + threadIdx.x; u < 12582912u; u += stride) {
    const float* in; u16* outp; size_t i;
    if (u < 2097152u)      { in = x;  outp = xb;  i = u; }
    else if (u < 6291456u) { in = wq; outp = wqb; i = u - 2097152u; }
    else if (u < 7340032u) { in = wk; outp = wkb; i = u - 6291456u; }
    else if (u < 8388608u) { in = wv; outp = wvb; i = u - 7340032u; }
    else                   { in = wo; outp = wob; i = u - 8388608u; }
    float4 f = ((const float4*)in)[i];
    ushort4 b;
    b.x = f2bf(f.x); b.y = f2bf(f.y); b.z = f2bf(f.z); b.w = f2bf(f.w);
    ((ushort4*)outp)[i] = b;
  }
}

// ---------------------------------------------------------------- counted-vmcnt GEMM
// C = A * B^T, bf16 row-major. BM=128, BN=64*NF, BK=32, 4 waves (2x2), wave
// tile 64 x 32*NF. TRIPLE-buffered LDS (60/48 KB -> 2 blocks/CU, 2 waves/SIMD)
// with raw s_barrier + counted vmcnt instead of __syncthreads' vmcnt(0) drain:
//   iter t: ds_read frags(buf cur) ; lgkmcnt(0)+schedbar ; s_barrier ;
//           stage(t+3 -> buf cur)  ; MFMA ; vmcnt(SGL)+schedbar ; s_barrier
// Invariants (verified): tile t+1 landed by iter t-1's vmcnt (stages in flight
// after iter-t stage = {t+2, t+3} = 2*SGL; vmcnt(SGL) waits t+2); the stage at
// iter t overwrites buf cur only after all waves' reads of it completed
// (lgkmcnt + barrier); tail re-stages tile KT-1 so counts stay uniform.
// BK=32 swizzle: 16B-unit u ^= (row ^ (row>>2)) & 3 on pre-swizzled global
// source (linear glds dest) + swizzled ds_read -> 2 lanes/slot = conflict-free.
template<int NF, bool QKV3>
__global__ __launch_bounds__(256, 2)
void gemm3b(const u16* __restrict__ A, const u16* __restrict__ B,
            void* __restrict__ Cq, u16* __restrict__ Ck, u16* __restrict__ Cv,
            int K) {
  constexpr int BN  = 64 * NF;
  constexpr int AT  = 128 * 32;          // 4096 u16 per A tile
  constexpr int BT  = BN * 32;           // u16 per B tile
  constexpr int BUFS = AT + BT;
  constexpr int BJ  = BT / 8 / 256;      // B glds per thread (3 or 2)
  __shared__ u16 lds[3 * BUFS];
  const int t = threadIdx.x;
  const int l = t & 63, lr = l & 15, lg = l >> 4;
  const int wid = t >> 6, wm = wid >> 1, wn = wid & 1;
  const int m0 = blockIdx.y * 128, n0 = blockIdx.x * BN;
  const int KT = K >> 5;
  const int wb = t & ~63;

  const u16* Ab = A + (size_t)m0 * K;
  const u16* Bb = B + (size_t)n0 * K;

#define STAGE3(TAU, BI) { \
  const int k0_ = (TAU) * 32; \
  u16* base_ = &lds[(BI) * BUFS]; \
  _Pragma("unroll") \
  for (int j = 0; j < 2; ++j) { \
    const int U = j * 256 + t; \
    const int row = U >> 2, u = U & 3; \
    const int us = u ^ ((row ^ (row >> 2)) & 3); \
    glds16(Ab + (size_t)row * K + k0_ + us * 8, base_ + (j * 256 + wb) * 8); \
  } \
  _Pragma("unroll") \
  for (int j = 0; j < BJ; ++j) { \
    const int U = j * 256 + t; \
    const int row = U >> 2, u = U & 3; \
    const int us = u ^ ((row ^ (row >> 2)) & 3); \
    glds16(Bb + (size_t)row * K + k0_ + us * 8, base_ + AT + (j * 256 + wb) * 8); \
  } }

  f32x4 acc[4][2 * NF] = {};

  // prologue: stage tiles 0,1,2 into bufs 0,1,2; wait tile 0 (2 stages in flight)
  STAGE3(0, 0);
  STAGE3(1, 1);
  STAGE3(2, 2);
  if constexpr (NF == 3) asm volatile("s_waitcnt vmcnt(10)" ::: "memory");
  else                   asm volatile("s_waitcnt vmcnt(8)" ::: "memory");
  __builtin_amdgcn_sched_barrier(0);
  __builtin_amdgcn_s_barrier();

  int cur = 0;
#pragma unroll 1
  for (int tau = 0; tau < KT; ++tau) {
    const u16* bufp = &lds[cur * BUFS];

    bf16x8 af[4], bfr[2 * NF];
#pragma unroll
    for (int mf = 0; mf < 4; ++mf) {
      const int row = wm * 64 + mf * 16 + lr;
      const int us = (lg ^ ((row ^ (row >> 2)) & 3)) * 8;
      af[mf] = *(const bf16x8*)&bufp[row * 32 + us];
    }
#pragma unroll
    for (int n = 0; n < 2 * NF; ++n) {
      const int row = wn * (32 * NF) + n * 16 + lr;
      const int us = (lg ^ ((row ^ (row >> 2)) & 3)) * 8;
      bfr[n] = *(const bf16x8*)&bufp[AT + row * 32 + us];
    }
    asm volatile("s_waitcnt lgkmcnt(0)" ::: "memory");
    __builtin_amdgcn_sched_barrier(0);
    __builtin_amdgcn_s_barrier();

    const int ts = (tau + 3 < KT) ? tau + 3 : KT - 1;
    STAGE3(ts, cur);

    __builtin_amdgcn_s_setprio(1);
#pragma unroll
    for (int mf = 0; mf < 4; ++mf)
#pragma unroll
      for (int n = 0; n < 2 * NF; ++n)
        acc[mf][n] = __builtin_amdgcn_mfma_f32_16x16x32_bf16(af[mf], bfr[n], acc[mf][n], 0, 0, 0);
    __builtin_amdgcn_s_setprio(0);

    if constexpr (NF == 3) asm volatile("s_waitcnt vmcnt(5)" ::: "memory");
    else                   asm volatile("s_waitcnt vmcnt(4)" ::: "memory");
    __builtin_amdgcn_sched_barrier(0);
    __builtin_amdgcn_s_barrier();
    cur = (cur == 2) ? 0 : cur + 1;
  }

  // epilogue; fragment cols are 16-aligned so QKV routing is per-fragment
#pragma unroll
  for (int mf = 0; mf < 4; ++mf) {
    const int row = m0 + wm * 64 + mf * 16 + lg * 4;
#pragma unroll
    for (int n = 0; n < 2 * NF; ++n) {
      const int gc = n0 + wn * (32 * NF) + n * 16 + lr;
#pragma unroll
      for (int r = 0; r < 4; ++r) {
        if constexpr (QKV3) {
          if (gc < 4096)
            ((u16*)Cq)[(size_t)(row + r) * 4096 + gc] = f2bf(acc[mf][n][r]);
          else if (gc < 5120)
            Ck[(size_t)(row + r) * 1024 + (gc - 4096)] = f2bf(acc[mf][n][r]);
          else
            Cv[(size_t)(row + r) * 1024 + (gc - 5120)] = f2bf(acc[mf][n][r]);
        } else {
          ((float*)Cq)[(size_t)(row + r) * 4096 + gc] = acc[mf][n][r];
        }
      }
    }
  }
#undef STAGE3
}

// ---------------------------------------------------------------- RoPE (q then k)
__global__ void rope_all(u16* __restrict__ qd, u16* __restrict__ kd,
                         const float* __restrict__ cosb, const float* __restrict__ sinb,
                         const int* __restrict__ sidx) {
  const int u = blockIdx.x * blockDim.x + threadIdx.x;
  u16* base; int s, b;
  if (u < 1048576) {
    base = qd + (size_t)u * 8;
    s = u >> 9;
    b = u & 15;
  } else if (u < 1310720) {
    const int u2 = u - 1048576;
    base = kd + (size_t)u2 * 8;
    s = u2 >> 7;
    b = u2 & 15;
  } else return;
  const int pos = sidx[s];
  const float4 c  = *(const float4*)&cosb[pos * 64 + b * 4];
  const float4 sn = *(const float4*)&sinb[pos * 64 + b * 4];
  uint4 raw = *(uint4*)base;
  u16* pe = (u16*)&raw;
  const float cc[4] = {c.x, c.y, c.z, c.w};
  const float ss[4] = {sn.x, sn.y, sn.z, sn.w};
#pragma unroll
  for (int j = 0; j < 4; ++j) {
    const float xr = bf2f(pe[2 * j]), xi = bf2f(pe[2 * j + 1]);
    pe[2 * j]     = f2bf(xr * cc[j] - xi * ss[j]);
    pe[2 * j + 1] = f2bf(xr * ss[j] + xi * cc[j]);
  }
  *(uint4*)base = raw;
}

// ---------------------------------------------------------------- V transpose
__global__ void transpose_v(const u16* __restrict__ v, u16* __restrict__ vt) {
  __shared__ u16 tile[32][33];
  const int tx = threadIdx.x, ty = threadIdx.y;
  const int c0 = blockIdx.x * 32, s0 = blockIdx.y * 32;
#pragma unroll
  for (int j = 0; j < 32; j += 8)
    tile[ty + j][tx] = v[(size_t)(s0 + ty + j) * EKV + c0 + tx];
  __syncthreads();
#pragma unroll
  for (int j = 0; j < 32; j += 8)
    vt[(size_t)(c0 + ty + j) * S_LEN + s0 + tx] = tile[tx][ty + j];
}

// ---------------------------------------------------------------- flash attention
// R9-vintage (unswapped, merged causal pair, shared-K dual QK^T). The R10
// swapped+merged variant spilled to scratch (192 MB WRITE_SIZE) — reverted.
#define ATTN_STAGE(TK, BUF) { \
  const int kv0s = (TK) * 64; \
  _Pragma("unroll") \
  for (int hh = 0; hh < 4; ++hh) { \
    const int f = hh * 256 + t; \
    { const int row = f >> 4, uu = f & 15, us = uu ^ (row & 7); \
      glds16(&k[(size_t)(kv0s + row) * EKV + kvh * HDIM + us * 8], &lK[BUF][(hh * 256 + wb) * 8]); } \
    { const int row = f >> 3, uu = f & 7, us = uu ^ (row & 7); \
      glds16(&vt[(size_t)(kvh * HDIM + row) * S_LEN + kv0s + us * 8], &lV[BUF][(hh * 256 + wb) * 8]); } \
  } }

#define SMPV(SC, O, MR, LR, Q0) { \
  _Pragma("unroll") \
  for (int n = 0; n < 4; ++n) { \
    const int kvc = kv0 + n * 16 + lr; \
    _Pragma("unroll") \
    for (int r = 0; r < 4; ++r) { \
      const int qr = (Q0) + lg * 4 + r; \
      const float vv = SC[n][r] * SC_LOG2E; \
      SC[n][r] = (kvc > qr) ? -1e30f : vv; \
    } \
  } \
  _Pragma("unroll") \
  for (int r = 0; r < 4; ++r) { \
    float v = fmaxf(fmaxf(SC[0][r], SC[1][r]), fmaxf(SC[2][r], SC[3][r])); \
    v = fmaxf(v, __shfl_xor(v, 1)); \
    v = fmaxf(v, __shfl_xor(v, 2)); \
    v = fmaxf(v, __shfl_xor(v, 4)); \
    v = fmaxf(v, __shfl_xor(v, 8)); \
    const float mn = fmaxf(MR[r], v); \
    const float sf = __builtin_amdgcn_exp2f(MR[r] - mn); \
    MR[r] = mn; \
    float rs = 0.f; \
    _Pragma("unroll") \
    for (int n = 0; n < 4; ++n) { \
      const float pv = __builtin_amdgcn_exp2f(SC[n][r] - mn); \
      SC[n][r] = pv; \
      rs += pv; \
    } \
    rs += __shfl_xor(rs, 1); \
    rs += __shfl_xor(rs, 2); \
    rs += __shfl_xor(rs, 4); \
    rs += __shfl_xor(rs, 8); \
    LR[r] = LR[r] * sf + rs; \
    _Pragma("unroll") \
    for (int nh = 0; nh < 8; ++nh) O[nh][r] *= sf; \
  } \
  _Pragma("unroll") \
  for (int n = 0; n < 4; ++n) \
    _Pragma("unroll") \
    for (int r = 0; r < 4; ++r) \
      lPw[(lg * 4 + r) * 72 + n * 16 + lr] = f2bf(SC[n][r]); \
  _Pragma("unroll") \
  for (int kc2 = 0; kc2 < 2; ++kc2) { \
    bf16x8 pa = *(const bf16x8*)&lPw[lr * 72 + kc2 * 32 + lg * 8]; \
    _Pragma("unroll") \
    for (int nh = 0; nh < 8; ++nh) { \
      const int row = nh * 16 + lr; \
      const int us = (kc2 * 4 + lg) ^ (row & 7); \
      bf16x8 bv = *(const bf16x8*)&lVc[row * 64 + us * 8]; \
      O[nh] = __builtin_amdgcn_mfma_f32_16x16x32_bf16(pa, bv, O[nh], 0, 0, 0); \
    } \
  } }

__global__ __launch_bounds__(256, 2)
void attn_fwd(const u16* __restrict__ q, const u16* __restrict__ k,
              const u16* __restrict__ vt, u16* __restrict__ ao) {
  __shared__ u16 lK[2][64 * 128];
  __shared__ u16 lV[2][128 * 64];
  __shared__ u16 lP[4 * 16 * 72];
  const int t = threadIdx.x, w = t >> 6, l = t & 63;
  const int lr = l & 15, lg = l >> 4;
  const int wb = t & ~63;
  const int p = blockIdx.x, h = blockIdx.y;
  const int kvh = h >> 2;
  u16* lPw = &lP[w * (16 * 72)];

  const int q0A = p * 64 + w * 16;
  const int q0B = (31 - p) * 64 + w * 16;
  const int nt = 32 - p;

  bf16x8 qaA[4], qaB[4];
#pragma unroll
  for (int kc = 0; kc < 4; ++kc) {
    qaA[kc] = *(const bf16x8*)&q[(size_t)(q0A + lr) * EQ + h * HDIM + kc * 32 + lg * 8];
    qaB[kc] = *(const bf16x8*)&q[(size_t)(q0B + lr) * EQ + h * HDIM + kc * 32 + lg * 8];
  }

  f32x4 oA[8] = {}, oB[8] = {};
  float mA[4], lA[4], mB[4], lB[4];
#pragma unroll
  for (int r = 0; r < 4; ++r) { mA[r] = -1e30f; lA[r] = 0.f; mB[r] = -1e30f; lB[r] = 0.f; }

  int cur = 0;
  ATTN_STAGE(0, 0);
  __syncthreads();

#pragma unroll 1
  for (int tk = 0; tk < nt; ++tk) {
    const int kv0 = tk * 64;
    if (tk + 1 < nt) ATTN_STAGE(tk + 1, cur ^ 1);
    const u16* lKc = lK[cur];
    const u16* lVc = lV[cur];

    if (tk <= p) {
      f32x4 scB[4] = {}, scA[4] = {};
#pragma unroll
      for (int n = 0; n < 4; ++n) {
#pragma unroll
        for (int kc = 0; kc < 4; ++kc) {
          const int row = n * 16 + lr;
          const int us = (kc * 4 + lg) ^ (row & 7);
          bf16x8 bk = *(const bf16x8*)&lKc[row * 128 + us * 8];
          scB[n] = __builtin_amdgcn_mfma_f32_16x16x32_bf16(qaB[kc], bk, scB[n], 0, 0, 0);
          scA[n] = __builtin_amdgcn_mfma_f32_16x16x32_bf16(qaA[kc], bk, scA[n], 0, 0, 0);
        }
      }
      SMPV(scB, oB, mB, lB, q0B);
      SMPV(scA, oA, mA, lA, q0A);
    } else {
      f32x4 scB[4] = {};
#pragma unroll
      for (int n = 0; n < 4; ++n) {
#pragma unroll
        for (int kc = 0; kc < 4; ++kc) {
          const int row = n * 16 + lr;
          const int us = (kc * 4 + lg) ^ (row & 7);
          bf16x8 bk = *(const bf16x8*)&lKc[row * 128 + us * 8];
          scB[n] = __builtin_amdgcn_mfma_f32_16x16x32_bf16(qaB[kc], bk, scB[n], 0, 0, 0);
        }
      }
      SMPV(scB, oB, mB, lB, q0B);
    }
    __syncthreads();
    cur ^= 1;
  }

#pragma unroll
  for (int nh = 0; nh < 8; ++nh)
#pragma unroll
    for (int r = 0; r < 4; ++r) {
      const int col = h * HDIM + nh * 16 + lr;
      ao[(size_t)(q0A + lg * 4 + r) * EQ + col] = f2bf(oA[nh][r] / lA[r]);
      ao[(size_t)(q0B + lg * 4 + r) * EQ + col] = f2bf(oB[nh][r] / lB[r]);
    }
}

// ---------------------------------------------------------------- launch
extern "C" void kernel_launch(void* const* d_in, const int* in_sizes, int n_in,
                              void* d_out, int out_size, void* d_ws, size_t ws_size,
                              hipStream_t stream) {
  (void)in_sizes; (void)n_in; (void)out_size; (void)ws_size;
  const float* x    = (const float*)d_in[0];
  const float* wq   = (const float*)d_in[1];
  const float* wk   = (const float*)d_in[2];
  const float* wv   = (const float*)d_in[3];
  const float* wo   = (const float*)d_in[4];
  const float* cosb = (const float*)d_in[7];
  const float* sinb = (const float*)d_in[8];
  const int*   sidx = (const int*)d_in[10];
  float* out = (float*)d_out;

  // workspace layout; wqb/wkb/wvb are contiguous so B_qkv = [wq;wk;wv]
  u16* ws  = (u16*)d_ws;
  u16* xb  = ws;                                  // 2048*4096
  u16* wqb = xb  + (size_t)S_LEN * DM;            // 4096*4096
  u16* wkb = wqb + (size_t)EQ * DM;               // 1024*4096
  u16* wvb = wkb + (size_t)EKV * DM;              // 1024*4096
  u16* wob = wvb + (size_t)EKV * DM;              // 4096*4096
  u16* qb  = wob + (size_t)DM * EQ;               // 2048*4096
  u16* kb  = qb  + (size_t)S_LEN * EQ;            // 2048*1024
  u16* vb  = kb  + (size_t)S_LEN * EKV;           // 2048*1024
  u16* vtb = vb  + (size_t)S_LEN * EKV;           // 1024*2048
  u16* aob = vtb + (size_t)S_LEN * EKV;           // 2048*4096

  cast_all<<<2048, 256, 0, stream>>>(x, wq, wk, wv, wo, xb, wqb, wkb, wvb, wob);
  // fused QKV projection: B = [wq;wk;wv] (6144 x 4096), BM=128/BN=192 -> 32x16 = 512 blocks (2/CU)
  gemm3b<3, true><<<dim3(32, 16), 256, 0, stream>>>(xb, wqb, qb, kb, vb, DM);
  rope_all<<<5120, 256, 0, stream>>>(qb, kb, cosb, sinb, sidx);
  transpose_v<<<dim3(EKV / 32, S_LEN / 32), dim3(32, 8), 0, stream>>>(vb, vtb);
  attn_fwd<<<dim3(16, NH), 256, 0, stream>>>(qb, kb, vtb, aob);
  // O projection: BM=128/BN=128 -> 32x16 = 512 blocks (2/CU)
  gemm3b<2, false><<<dim3(32, 16), 256, 0, stream>>>(aob, wob, out, nullptr, nullptr, EQ);
}

// Round 12
// 340.336 us; speedup vs baseline: 1.1391x; 1.0613x over previous
//
#include <hip/hip_runtime.h>
#include <cstdint>
#include <cstddef>

#define S_LEN 2048
#define DM    4096
#define NH    32
#define NKV   8
#define HDIM  128
#define EQ    4096   // NH*HDIM
#define EKV   1024   // NKV*HDIM
#define SC_LOG2E 0.1275325477889277f   // (1/sqrt(128)) * log2(e)

typedef unsigned short u16;
typedef short bf16x8 __attribute__((ext_vector_type(8)));
typedef float f32x4  __attribute__((ext_vector_type(4)));

__device__ __forceinline__ u16 f2bf(float f) {
  union { float f; unsigned u; } v; v.f = f;
  unsigned r = v.u + 0x7FFFu + ((v.u >> 16) & 1u);
  return (u16)(r >> 16);
}
__device__ __forceinline__ float bf2f(u16 b) {
  union { unsigned u; float f; } v; v.u = ((unsigned)b) << 16;
  return v.f;
}
__device__ __forceinline__ void glds16(const void* g, void* l) {
  __builtin_amdgcn_global_load_lds((const __attribute__((address_space(1))) void*)g,
                                   (__attribute__((address_space(3))) void*)l, 16, 0, 0);
}

// ---------------------------------------------------------------- cast fp32->bf16
__global__ void cast_all(const float* __restrict__ x, const float* __restrict__ wq,
                         const float* __restrict__ wk, const float* __restrict__ wv,
                         const float* __restrict__ wo,
                         u16* __restrict__ xb, u16* __restrict__ wqb,
                         u16* __restrict__ wkb, u16* __restrict__ wvb,
                         u16* __restrict__ wob) {
  const size_t stride = (size_t)gridDim.x * blockDim.x;
  for (size_t u = (size_t)blockIdx.x * blockDim.x + threadIdx.x; u < 12582912u; u += stride) {
    const float* in; u16* outp; size_t i;
    if (u < 2097152u)      { in = x;  outp = xb;  i = u; }
    else if (u < 6291456u) { in = wq; outp = wqb; i = u - 2097152u; }
    else if (u < 7340032u) { in = wk; outp = wkb; i = u - 6291456u; }
    else if (u < 8388608u) { in = wv; outp = wvb; i = u - 7340032u; }
    else                   { in = wo; outp = wob; i = u - 8388608u; }
    float4 f = ((const float4*)in)[i];
    ushort4 b;
    b.x = f2bf(f.x); b.y = f2bf(f.y); b.z = f2bf(f.z); b.w = f2bf(f.w);
    ((ushort4*)outp)[i] = b;
  }
}

// ---------------------------------------------------------------- 2-phase GEMM, BM=128, BN=64*NF
// (R8 inner structure verbatim — proven 104/70 us, MfmaUtil 44%, 0 conflicts.)
// NEW: XCD-aware block swizzle. Grid launched 1D (512). HW round-robins
// consecutive bids across the 8 XCDs, so bids {8j+k} land on XCD k; we map
// j -> a 4-col x 16-row patch of the (32 x 16) tile grid per XCD, iterated
// columns-outer / rows-inner: the 1.5 MB B panel stays L2-resident while the
// 16 A panels stream (working set ~2.5 MB < 4 MB XCD L2). Cuts L3->L2 panel
// traffic ~1.34 GB -> ~0.56 GB per dispatch. Bijective (512 = 8 * 64).
template<int UN>
__device__ __forceinline__ void stage_t(const u16* __restrict__ g, int ldg, int k0,
                                        u16* ldsp, int t) {
  const int wb = t & ~63;
#pragma unroll
  for (int j = 0; j < UN / 256; ++j) {
    const int U = j * 256 + t;
    const int row = U >> 3, u = U & 7;
    const int uu = u ^ (row & 7);
    glds16(g + (size_t)row * ldg + k0 + uu * 8, ldsp + (size_t)(j * 256 + wb) * 8);
  }
}

template<int NF, bool QKV3>
__global__ __launch_bounds__(256, 2)
void gemm2p(const u16* __restrict__ A, const u16* __restrict__ B,
            void* __restrict__ Cq, u16* __restrict__ Ck, u16* __restrict__ Cv,
            int K) {
  constexpr int BN = 64 * NF;
  constexpr int AT = 128 * 64;        // u16 per A tile (8192)
  constexpr int BT = BN * 64;         // u16 per B tile
  __shared__ u16 lds[2 * (AT + BT)];  // A0 @0, A1 @AT, B0 @2*AT, B1 @2*AT+BT
  const int t = threadIdx.x;
  const int l = t & 63, lr = l & 15, lg = l >> 4;
  const int wid = t >> 6, wm = wid >> 1, wn = wid & 1;

  // XCD swizzle: bid = 8j+k -> XCD k; patch k = cols [4k,4k+4) x rows [0,16),
  // columns-outer (j>>4 = px), rows-inner (j&15 = py).
  const int bid = blockIdx.x;
  const int xcd = bid & 7, j = bid >> 3;
  const int bx = xcd * 4 + (j >> 4);
  const int by = j & 15;
  const int m0 = by * 128, n0 = bx * BN;
  const int KT = K >> 6;

  const u16* Ab = A + (size_t)m0 * K;
  const u16* Bb = B + (size_t)n0 * K;

  f32x4 acc[4][2 * NF] = {};

  stage_t<1024>(Ab, K, 0, &lds[0], t);
  stage_t<BT / 8>(Bb, K, 0, &lds[2 * AT], t);
  __syncthreads();

  int cur = 0;
#pragma unroll 1
  for (int tau = 0; tau < KT; ++tau) {
    const int kn = (tau + 1 < KT ? tau + 1 : KT - 1) * 64;
    stage_t<1024>(Ab, K, kn, &lds[(cur ^ 1) * AT], t);
    stage_t<BT / 8>(Bb, K, kn, &lds[2 * AT + (cur ^ 1) * BT], t);

    const int aBase = cur * AT;
    const int bBase = 2 * AT + cur * BT;

    bf16x8 af[4][2];
#pragma unroll
    for (int mf = 0; mf < 4; ++mf)
#pragma unroll
      for (int kk = 0; kk < 2; ++kk) {
        const int row = wm * 64 + mf * 16 + lr;
        const int uu = ((kk * 4 + lg) ^ (row & 7)) * 8;
        af[mf][kk] = *(const bf16x8*)&lds[aBase + row * 64 + uu];
      }

#pragma unroll
    for (int n = 0; n < 2 * NF; ++n) {
      const int brow = wn * (32 * NF) + n * 16 + lr;
      const int u0 = ((0 * 4 + lg) ^ (brow & 7)) * 8;
      const int u1 = ((1 * 4 + lg) ^ (brow & 7)) * 8;
      bf16x8 b0 = *(const bf16x8*)&lds[bBase + brow * 64 + u0];
      bf16x8 b1 = *(const bf16x8*)&lds[bBase + brow * 64 + u1];
#pragma unroll
      for (int mf = 0; mf < 4; ++mf) {
        acc[mf][n] = __builtin_amdgcn_mfma_f32_16x16x32_bf16(af[mf][0], b0, acc[mf][n], 0, 0, 0);
        acc[mf][n] = __builtin_amdgcn_mfma_f32_16x16x32_bf16(af[mf][1], b1, acc[mf][n], 0, 0, 0);
      }
    }
    __syncthreads();
    cur ^= 1;
  }

  // epilogue; fragment cols are 16-aligned so QKV routing is per-fragment
#pragma unroll
  for (int mf = 0; mf < 4; ++mf) {
    const int row = m0 + wm * 64 + mf * 16 + lg * 4;
#pragma unroll
    for (int n = 0; n < 2 * NF; ++n) {
      const int gc = n0 + wn * (32 * NF) + n * 16 + lr;
#pragma unroll
      for (int r = 0; r < 4; ++r) {
        if constexpr (QKV3) {
          if (gc < 4096)
            ((u16*)Cq)[(size_t)(row + r) * 4096 + gc] = f2bf(acc[mf][n][r]);
          else if (gc < 5120)
            Ck[(size_t)(row + r) * 1024 + (gc - 4096)] = f2bf(acc[mf][n][r]);
          else
            Cv[(size_t)(row + r) * 1024 + (gc - 5120)] = f2bf(acc[mf][n][r]);
        } else {
          ((float*)Cq)[(size_t)(row + r) * 4096 + gc] = acc[mf][n][r];
        }
      }
    }
  }
}

// ---------------------------------------------------------------- RoPE (q then k)
__global__ void rope_all(u16* __restrict__ qd, u16* __restrict__ kd,
                         const float* __restrict__ cosb, const float* __restrict__ sinb,
                         const int* __restrict__ sidx) {
  const int u = blockIdx.x * blockDim.x + threadIdx.x;
  u16* base; int s, b;
  if (u < 1048576) {
    base = qd + (size_t)u * 8;
    s = u >> 9;
    b = u & 15;
  } else if (u < 1310720) {
    const int u2 = u - 1048576;
    base = kd + (size_t)u2 * 8;
    s = u2 >> 7;
    b = u2 & 15;
  } else return;
  const int pos = sidx[s];
  const float4 c  = *(const float4*)&cosb[pos * 64 + b * 4];
  const float4 sn = *(const float4*)&sinb[pos * 64 + b * 4];
  uint4 raw = *(uint4*)base;
  u16* pe = (u16*)&raw;
  const float cc[4] = {c.x, c.y, c.z, c.w};
  const float ss[4] = {sn.x, sn.y, sn.z, sn.w};
#pragma unroll
  for (int j = 0; j < 4; ++j) {
    const float xr = bf2f(pe[2 * j]), xi = bf2f(pe[2 * j + 1]);
    pe[2 * j]     = f2bf(xr * cc[j] - xi * ss[j]);
    pe[2 * j + 1] = f2bf(xr * ss[j] + xi * cc[j]);
  }
  *(uint4*)base = raw;
}

// ---------------------------------------------------------------- V transpose
__global__ void transpose_v(const u16* __restrict__ v, u16* __restrict__ vt) {
  __shared__ u16 tile[32][33];
  const int tx = threadIdx.x, ty = threadIdx.y;
  const int c0 = blockIdx.x * 32, s0 = blockIdx.y * 32;
#pragma unroll
  for (int j = 0; j < 32; j += 8)
    tile[ty + j][tx] = v[(size_t)(s0 + ty + j) * EKV + c0 + tx];
  __syncthreads();
#pragma unroll
  for (int j = 0; j < 32; j += 8)
    vt[(size_t)(c0 + ty + j) * S_LEN + s0 + tx] = tile[tx][ty + j];
}

// ---------------------------------------------------------------- flash attention
// R9-vintage (unswapped, merged causal pair, shared-K dual QK^T).
#define ATTN_STAGE(TK, BUF) { \
  const int kv0s = (TK) * 64; \
  _Pragma("unroll") \
  for (int hh = 0; hh < 4; ++hh) { \
    const int f = hh * 256 + t; \
    { const int row = f >> 4, uu = f & 15, us = uu ^ (row & 7); \
      glds16(&k[(size_t)(kv0s + row) * EKV + kvh * HDIM + us * 8], &lK[BUF][(hh * 256 + wb) * 8]); } \
    { const int row = f >> 3, uu = f & 7, us = uu ^ (row & 7); \
      glds16(&vt[(size_t)(kvh * HDIM + row) * S_LEN + kv0s + us * 8], &lV[BUF][(hh * 256 + wb) * 8]); } \
  } }

#define SMPV(SC, O, MR, LR, Q0) { \
  _Pragma("unroll") \
  for (int n = 0; n < 4; ++n) { \
    const int kvc = kv0 + n * 16 + lr; \
    _Pragma("unroll") \
    for (int r = 0; r < 4; ++r) { \
      const int qr = (Q0) + lg * 4 + r; \
      const float vv = SC[n][r] * SC_LOG2E; \
      SC[n][r] = (kvc > qr) ? -1e30f : vv; \
    } \
  } \
  _Pragma("unroll") \
  for (int r = 0; r < 4; ++r) { \
    float v = fmaxf(fmaxf(SC[0][r], SC[1][r]), fmaxf(SC[2][r], SC[3][r])); \
    v = fmaxf(v, __shfl_xor(v, 1)); \
    v = fmaxf(v, __shfl_xor(v, 2)); \
    v = fmaxf(v, __shfl_xor(v, 4)); \
    v = fmaxf(v, __shfl_xor(v, 8)); \
    const float mn = fmaxf(MR[r], v); \
    const float sf = __builtin_amdgcn_exp2f(MR[r] - mn); \
    MR[r] = mn; \
    float rs = 0.f; \
    _Pragma("unroll") \
    for (int n = 0; n < 4; ++n) { \
      const float pv = __builtin_amdgcn_exp2f(SC[n][r] - mn); \
      SC[n][r] = pv; \
      rs += pv; \
    } \
    rs += __shfl_xor(rs, 1); \
    rs += __shfl_xor(rs, 2); \
    rs += __shfl_xor(rs, 4); \
    rs += __shfl_xor(rs, 8); \
    LR[r] = LR[r] * sf + rs; \
    _Pragma("unroll") \
    for (int nh = 0; nh < 8; ++nh) O[nh][r] *= sf; \
  } \
  _Pragma("unroll") \
  for (int n = 0; n < 4; ++n) \
    _Pragma("unroll") \
    for (int r = 0; r < 4; ++r) \
      lPw[(lg * 4 + r) * 72 + n * 16 + lr] = f2bf(SC[n][r]); \
  _Pragma("unroll") \
  for (int kc2 = 0; kc2 < 2; ++kc2) { \
    bf16x8 pa = *(const bf16x8*)&lPw[lr * 72 + kc2 * 32 + lg * 8]; \
    _Pragma("unroll") \
    for (int nh = 0; nh < 8; ++nh) { \
      const int row = nh * 16 + lr; \
      const int us = (kc2 * 4 + lg) ^ (row & 7); \
      bf16x8 bv = *(const bf16x8*)&lVc[row * 64 + us * 8]; \
      O[nh] = __builtin_amdgcn_mfma_f32_16x16x32_bf16(pa, bv, O[nh], 0, 0, 0); \
    } \
  } }

__global__ __launch_bounds__(256, 2)
void attn_fwd(const u16* __restrict__ q, const u16* __restrict__ k,
              const u16* __restrict__ vt, u16* __restrict__ ao) {
  __shared__ u16 lK[2][64 * 128];
  __shared__ u16 lV[2][128 * 64];
  __shared__ u16 lP[4 * 16 * 72];
  const int t = threadIdx.x, w = t >> 6, l = t & 63;
  const int lr = l & 15, lg = l >> 4;
  const int wb = t & ~63;
  const int p = blockIdx.x, h = blockIdx.y;
  const int kvh = h >> 2;
  u16* lPw = &lP[w * (16 * 72)];

  const int q0A = p * 64 + w * 16;
  const int q0B = (31 - p) * 64 + w * 16;
  const int nt = 32 - p;

  bf16x8 qaA[4], qaB[4];
#pragma unroll
  for (int kc = 0; kc < 4; ++kc) {
    qaA[kc] = *(const bf16x8*)&q[(size_t)(q0A + lr) * EQ + h * HDIM + kc * 32 + lg * 8];
    qaB[kc] = *(const bf16x8*)&q[(size_t)(q0B + lr) * EQ + h * HDIM + kc * 32 + lg * 8];
  }

  f32x4 oA[8] = {}, oB[8] = {};
  float mA[4], lA[4], mB[4], lB[4];
#pragma unroll
  for (int r = 0; r < 4; ++r) { mA[r] = -1e30f; lA[r] = 0.f; mB[r] = -1e30f; lB[r] = 0.f; }

  int cur = 0;
  ATTN_STAGE(0, 0);
  __syncthreads();

#pragma unroll 1
  for (int tk = 0; tk < nt; ++tk) {
    const int kv0 = tk * 64;
    if (tk + 1 < nt) ATTN_STAGE(tk + 1, cur ^ 1);
    const u16* lKc = lK[cur];
    const u16* lVc = lV[cur];

    if (tk <= p) {
      f32x4 scB[4] = {}, scA[4] = {};
#pragma unroll
      for (int n = 0; n < 4; ++n) {
#pragma unroll
        for (int kc = 0; kc < 4; ++kc) {
          const int row = n * 16 + lr;
          const int us = (kc * 4 + lg) ^ (row & 7);
          bf16x8 bk = *(const bf16x8*)&lKc[row * 128 + us * 8];
          scB[n] = __builtin_amdgcn_mfma_f32_16x16x32_bf16(qaB[kc], bk, scB[n], 0, 0, 0);
          scA[n] = __builtin_amdgcn_mfma_f32_16x16x32_bf16(qaA[kc], bk, scA[n], 0, 0, 0);
        }
      }
      SMPV(scB, oB, mB, lB, q0B);
      SMPV(scA, oA, mA, lA, q0A);
    } else {
      f32x4 scB[4] = {};
#pragma unroll
      for (int n = 0; n < 4; ++n) {
#pragma unroll
        for (int kc = 0; kc < 4; ++kc) {
          const int row = n * 16 + lr;
          const int us = (kc * 4 + lg) ^ (row & 7);
          bf16x8 bk = *(const bf16x8*)&lKc[row * 128 + us * 8];
          scB[n] = __builtin_amdgcn_mfma_f32_16x16x32_bf16(qaB[kc], bk, scB[n], 0, 0, 0);
        }
      }
      SMPV(scB, oB, mB, lB, q0B);
    }
    __syncthreads();
    cur ^= 1;
  }

#pragma unroll
  for (int nh = 0; nh < 8; ++nh)
#pragma unroll
    for (int r = 0; r < 4; ++r) {
      const int col = h * HDIM + nh * 16 + lr;
      ao[(size_t)(q0A + lg * 4 + r) * EQ + col] = f2bf(oA[nh][r] / lA[r]);
      ao[(size_t)(q0B + lg * 4 + r) * EQ + col] = f2bf(oB[nh][r] / lB[r]);
    }
}

// ---------------------------------------------------------------- launch
extern "C" void kernel_launch(void* const* d_in, const int* in_sizes, int n_in,
                              void* d_out, int out_size, void* d_ws, size_t ws_size,
                              hipStream_t stream) {
  (void)in_sizes; (void)n_in; (void)out_size; (void)ws_size;
  const float* x    = (const float*)d_in[0];
  const float* wq   = (const float*)d_in[1];
  const float* wk   = (const float*)d_in[2];
  const float* wv   = (const float*)d_in[3];
  const float* wo   = (const float*)d_in[4];
  const float* cosb = (const float*)d_in[7];
  const float* sinb = (const float*)d_in[8];
  const int*   sidx = (const int*)d_in[10];
  float* out = (float*)d_out;

  // workspace layout; wqb/wkb/wvb are contiguous so B_qkv = [wq;wk;wv]
  u16* ws  = (u16*)d_ws;
  u16* xb  = ws;                                  // 2048*4096
  u16* wqb = xb  + (size_t)S_LEN * DM;            // 4096*4096
  u16* wkb = wqb + (size_t)EQ * DM;               // 1024*4096
  u16* wvb = wkb + (size_t)EKV * DM;              // 1024*4096
  u16* wob = wvb + (size_t)EKV * DM;              // 4096*4096
  u16* qb  = wob + (size_t)DM * EQ;               // 2048*4096
  u16* kb  = qb  + (size_t)S_LEN * EQ;            // 2048*1024
  u16* vb  = kb  + (size_t)S_LEN * EKV;           // 2048*1024
  u16* vtb = vb  + (size_t)S_LEN * EKV;           // 1024*2048
  u16* aob = vtb + (size_t)S_LEN * EKV;           // 2048*4096

  cast_all<<<2048, 256, 0, stream>>>(x, wq, wk, wv, wo, xb, wqb, wkb, wvb, wob);
  // fused QKV projection: B = [wq;wk;wv] (6144 x 4096); 1D grid 512, XCD-swizzled
  gemm2p<3, true><<<512, 256, 0, stream>>>(xb, wqb, qb, kb, vb, DM);
  rope_all<<<5120, 256, 0, stream>>>(qb, kb, cosb, sinb, sidx);
  transpose_v<<<dim3(EKV / 32, S_LEN / 32), dim3(32, 8), 0, stream>>>(vb, vtb);
  attn_fwd<<<dim3(16, NH), 256, 0, stream>>>(qb, kb, vtb, aob);
  // O projection: 1D grid 512, XCD-swizzled
  gemm2p<2, false><<<512, 256, 0, stream>>>(aob, wob, out, nullptr, nullptr, EQ);
}

// Round 13
// 321.591 us; speedup vs baseline: 1.2055x; 1.0583x over previous
//
#include <hip/hip_runtime.h>
#include <cstdint>
#include <cstddef>

#define S_LEN 2048
#define DM    4096
#define NH    32
#define NKV   8
#define HDIM  128
#define EQ    4096   // NH*HDIM
#define EKV   1024   // NKV*HDIM
#define SC_LOG2E 0.1275325477889277f   // (1/sqrt(128)) * log2(e)

typedef unsigned short u16;
typedef short bf16x8 __attribute__((ext_vector_type(8)));
typedef float f32x4  __attribute__((ext_vector_type(4)));

__device__ __forceinline__ u16 f2bf(float f) {
  union { float f; unsigned u; } v; v.f = f;
  unsigned r = v.u + 0x7FFFu + ((v.u >> 16) & 1u);
  return (u16)(r >> 16);
}
__device__ __forceinline__ float bf2f(u16 b) {
  union { unsigned u; float f; } v; v.u = ((unsigned)b) << 16;
  return v.f;
}
__device__ __forceinline__ void glds16(const void* g, void* l) {
  __builtin_amdgcn_global_load_lds((const __attribute__((address_space(1))) void*)g,
                                   (__attribute__((address_space(3))) void*)l, 16, 0, 0);
}

// ---------------------------------------------------------------- cast fp32->bf16
__global__ void cast_all(const float* __restrict__ x, const float* __restrict__ wq,
                         const float* __restrict__ wk, const float* __restrict__ wv,
                         const float* __restrict__ wo,
                         u16* __restrict__ xb, u16* __restrict__ wqb,
                         u16* __restrict__ wkb, u16* __restrict__ wvb,
                         u16* __restrict__ wob) {
  const size_t stride = (size_t)gridDim.x * blockDim.x;
  for (size_t u = (size_t)blockIdx.x * blockDim.x + threadIdx.x; u < 12582912u; u += stride) {
    const float* in; u16* outp; size_t i;
    if (u < 2097152u)      { in = x;  outp = xb;  i = u; }
    else if (u < 6291456u) { in = wq; outp = wqb; i = u - 2097152u; }
    else if (u < 7340032u) { in = wk; outp = wkb; i = u - 6291456u; }
    else if (u < 8388608u) { in = wv; outp = wvb; i = u - 7340032u; }
    else                   { in = wo; outp = wob; i = u - 8388608u; }
    float4 f = ((const float4*)in)[i];
    ushort4 b;
    b.x = f2bf(f.x); b.y = f2bf(f.y); b.z = f2bf(f.z); b.w = f2bf(f.w);
    ((ushort4*)outp)[i] = b;
  }
}

// ---------------------------------------------------------------- 2-phase GEMM, BM=128, BN=64*NF
// (R8 inner structure + R11 XCD swizzle — measured: QKV ~88us, O ~60us, 0 conflicts.)
// 1D grid 512; bid = 8j+k -> XCD k owns a 4-col x 16-row patch of the 32x16
// tile grid, columns-outer: B panel stays L2-resident per XCD.
template<int UN>
__device__ __forceinline__ void stage_t(const u16* __restrict__ g, int ldg, int k0,
                                        u16* ldsp, int t) {
  const int wb = t & ~63;
#pragma unroll
  for (int j = 0; j < UN / 256; ++j) {
    const int U = j * 256 + t;
    const int row = U >> 3, u = U & 7;
    const int uu = u ^ (row & 7);
    glds16(g + (size_t)row * ldg + k0 + uu * 8, ldsp + (size_t)(j * 256 + wb) * 8);
  }
}

template<int NF, bool QKV3>
__global__ __launch_bounds__(256, 2)
void gemm2p(const u16* __restrict__ A, const u16* __restrict__ B,
            void* __restrict__ Cq, u16* __restrict__ Ck, u16* __restrict__ Cv,
            int K) {
  constexpr int BN = 64 * NF;
  constexpr int AT = 128 * 64;        // u16 per A tile (8192)
  constexpr int BT = BN * 64;         // u16 per B tile
  __shared__ u16 lds[2 * (AT + BT)];  // A0 @0, A1 @AT, B0 @2*AT, B1 @2*AT+BT
  const int t = threadIdx.x;
  const int l = t & 63, lr = l & 15, lg = l >> 4;
  const int wid = t >> 6, wm = wid >> 1, wn = wid & 1;

  const int bid = blockIdx.x;
  const int xcd = bid & 7, j = bid >> 3;
  const int bx = xcd * 4 + (j >> 4);
  const int by = j & 15;
  const int m0 = by * 128, n0 = bx * BN;
  const int KT = K >> 6;

  const u16* Ab = A + (size_t)m0 * K;
  const u16* Bb = B + (size_t)n0 * K;

  f32x4 acc[4][2 * NF] = {};

  stage_t<1024>(Ab, K, 0, &lds[0], t);
  stage_t<BT / 8>(Bb, K, 0, &lds[2 * AT], t);
  __syncthreads();

  int cur = 0;
#pragma unroll 1
  for (int tau = 0; tau < KT; ++tau) {
    const int kn = (tau + 1 < KT ? tau + 1 : KT - 1) * 64;
    stage_t<1024>(Ab, K, kn, &lds[(cur ^ 1) * AT], t);
    stage_t<BT / 8>(Bb, K, kn, &lds[2 * AT + (cur ^ 1) * BT], t);

    const int aBase = cur * AT;
    const int bBase = 2 * AT + cur * BT;

    bf16x8 af[4][2];
#pragma unroll
    for (int mf = 0; mf < 4; ++mf)
#pragma unroll
      for (int kk = 0; kk < 2; ++kk) {
        const int row = wm * 64 + mf * 16 + lr;
        const int uu = ((kk * 4 + lg) ^ (row & 7)) * 8;
        af[mf][kk] = *(const bf16x8*)&lds[aBase + row * 64 + uu];
      }

#pragma unroll
    for (int n = 0; n < 2 * NF; ++n) {
      const int brow = wn * (32 * NF) + n * 16 + lr;
      const int u0 = ((0 * 4 + lg) ^ (brow & 7)) * 8;
      const int u1 = ((1 * 4 + lg) ^ (brow & 7)) * 8;
      bf16x8 b0 = *(const bf16x8*)&lds[bBase + brow * 64 + u0];
      bf16x8 b1 = *(const bf16x8*)&lds[bBase + brow * 64 + u1];
#pragma unroll
      for (int mf = 0; mf < 4; ++mf) {
        acc[mf][n] = __builtin_amdgcn_mfma_f32_16x16x32_bf16(af[mf][0], b0, acc[mf][n], 0, 0, 0);
        acc[mf][n] = __builtin_amdgcn_mfma_f32_16x16x32_bf16(af[mf][1], b1, acc[mf][n], 0, 0, 0);
      }
    }
    __syncthreads();
    cur ^= 1;
  }

  // epilogue; fragment cols are 16-aligned so QKV routing is per-fragment
#pragma unroll
  for (int mf = 0; mf < 4; ++mf) {
    const int row = m0 + wm * 64 + mf * 16 + lg * 4;
#pragma unroll
    for (int n = 0; n < 2 * NF; ++n) {
      const int gc = n0 + wn * (32 * NF) + n * 16 + lr;
#pragma unroll
      for (int r = 0; r < 4; ++r) {
        if constexpr (QKV3) {
          if (gc < 4096)
            ((u16*)Cq)[(size_t)(row + r) * 4096 + gc] = f2bf(acc[mf][n][r]);
          else if (gc < 5120)
            Ck[(size_t)(row + r) * 1024 + (gc - 4096)] = f2bf(acc[mf][n][r]);
          else
            Cv[(size_t)(row + r) * 1024 + (gc - 5120)] = f2bf(acc[mf][n][r]);
        } else {
          ((float*)Cq)[(size_t)(row + r) * 4096 + gc] = acc[mf][n][r];
        }
      }
    }
  }
}

// ---------------------------------------------------------------- RoPE (q then k)
__global__ void rope_all(u16* __restrict__ qd, u16* __restrict__ kd,
                         const float* __restrict__ cosb, const float* __restrict__ sinb,
                         const int* __restrict__ sidx) {
  const int u = blockIdx.x * blockDim.x + threadIdx.x;
  u16* base; int s, b;
  if (u < 1048576) {
    base = qd + (size_t)u * 8;
    s = u >> 9;
    b = u & 15;
  } else if (u < 1310720) {
    const int u2 = u - 1048576;
    base = kd + (size_t)u2 * 8;
    s = u2 >> 7;
    b = u2 & 15;
  } else return;
  const int pos = sidx[s];
  const float4 c  = *(const float4*)&cosb[pos * 64 + b * 4];
  const float4 sn = *(const float4*)&sinb[pos * 64 + b * 4];
  uint4 raw = *(uint4*)base;
  u16* pe = (u16*)&raw;
  const float cc[4] = {c.x, c.y, c.z, c.w};
  const float ss[4] = {sn.x, sn.y, sn.z, sn.w};
#pragma unroll
  for (int j = 0; j < 4; ++j) {
    const float xr = bf2f(pe[2 * j]), xi = bf2f(pe[2 * j + 1]);
    pe[2 * j]     = f2bf(xr * cc[j] - xi * ss[j]);
    pe[2 * j + 1] = f2bf(xr * ss[j] + xi * cc[j]);
  }
  *(uint4*)base = raw;
}

// ---------------------------------------------------------------- V transpose
__global__ void transpose_v(const u16* __restrict__ v, u16* __restrict__ vt) {
  __shared__ u16 tile[32][33];
  const int tx = threadIdx.x, ty = threadIdx.y;
  const int c0 = blockIdx.x * 32, s0 = blockIdx.y * 32;
#pragma unroll
  for (int j = 0; j < 32; j += 8)
    tile[ty + j][tx] = v[(size_t)(s0 + ty + j) * EKV + c0 + tx];
  __syncthreads();
#pragma unroll
  for (int j = 0; j < 32; j += 8)
    vt[(size_t)(c0 + ty + j) * S_LEN + s0 + tx] = tile[tx][ty + j];
}

// ---------------------------------------------------------------- flash attention
// R6-vintage SPLIT causal pairing (measured-best ~60us): block (p,h) runs
// q-tile p then q-tile 31-p as two sequential KV sweeps (33 balanced tile
// steps). ONE q-tile's state live at a time (o[8],m[4],l[4],qa[4]) — the
// merged-pair variants regressed to 122us via register pressure (R12 PMC).
// K/V double-buffered: stage(tk+1 -> buf^1) issued before computing tile tk,
// one __syncthreads per tile. 74.7 KB LDS -> 2 blocks/CU.
#define ATTN_STAGE(TK, BUF) { \
  const int kv0s = (TK) * 64; \
  _Pragma("unroll") \
  for (int hh = 0; hh < 4; ++hh) { \
    const int f = hh * 256 + t; \
    { const int row = f >> 4, uu = f & 15, us = uu ^ (row & 7); \
      glds16(&k[(size_t)(kv0s + row) * EKV + kvh * HDIM + us * 8], &lK[BUF][(hh * 256 + wb) * 8]); } \
    { const int row = f >> 3, uu = f & 7, us = uu ^ (row & 7); \
      glds16(&vt[(size_t)(kvh * HDIM + row) * S_LEN + kv0s + us * 8], &lV[BUF][(hh * 256 + wb) * 8]); } \
  } }

__global__ __launch_bounds__(256, 2)
void attn_fwd(const u16* __restrict__ q, const u16* __restrict__ k,
              const u16* __restrict__ vt, u16* __restrict__ ao) {
  __shared__ u16 lK[2][64 * 128];
  __shared__ u16 lV[2][128 * 64];
  __shared__ u16 lP[4 * 16 * 72];
  const int t = threadIdx.x, w = t >> 6, l = t & 63;
  const int lr = l & 15, lg = l >> 4;
  const int wb = t & ~63;
  const int p = blockIdx.x, h = blockIdx.y;
  const int kvh = h >> 2;
  u16* lPw = &lP[w * (16 * 72)];

#pragma unroll 1
  for (int ph = 0; ph < 2; ++ph) {
    const int qt = ph ? (31 - p) : p;
    const int q0 = qt * 64 + w * 16;
    const int nt = qt + 1;

    bf16x8 qa[4];
#pragma unroll
    for (int kc = 0; kc < 4; ++kc)
      qa[kc] = *(const bf16x8*)&q[(size_t)(q0 + lr) * EQ + h * HDIM + kc * 32 + lg * 8];

    f32x4 o[8] = {};
    float mrun[4], lrun[4];
#pragma unroll
    for (int r = 0; r < 4; ++r) { mrun[r] = -1e30f; lrun[r] = 0.f; }

    int cur = 0;
    ATTN_STAGE(0, 0);
    __syncthreads();

#pragma unroll 1
    for (int tk = 0; tk < nt; ++tk) {
      const int kv0 = tk * 64;
      if (tk + 1 < nt) ATTN_STAGE(tk + 1, cur ^ 1);
      const u16* lKc = lK[cur];
      const u16* lVc = lV[cur];

      f32x4 sc[4] = {};
#pragma unroll
      for (int n = 0; n < 4; ++n) {
#pragma unroll
        for (int kc = 0; kc < 4; ++kc) {
          const int row = n * 16 + lr;
          const int us = (kc * 4 + lg) ^ (row & 7);
          bf16x8 bk = *(const bf16x8*)&lKc[row * 128 + us * 8];
          sc[n] = __builtin_amdgcn_mfma_f32_16x16x32_bf16(qa[kc], bk, sc[n], 0, 0, 0);
        }
      }

#pragma unroll
      for (int n = 0; n < 4; ++n) {
        const int kvc = kv0 + n * 16 + lr;
#pragma unroll
        for (int r = 0; r < 4; ++r) {
          const int qr = q0 + lg * 4 + r;
          const float v = sc[n][r] * SC_LOG2E;
          sc[n][r] = (kvc > qr) ? -1e30f : v;
        }
      }
#pragma unroll
      for (int r = 0; r < 4; ++r) {
        float v = fmaxf(fmaxf(sc[0][r], sc[1][r]), fmaxf(sc[2][r], sc[3][r]));
        v = fmaxf(v, __shfl_xor(v, 1));
        v = fmaxf(v, __shfl_xor(v, 2));
        v = fmaxf(v, __shfl_xor(v, 4));
        v = fmaxf(v, __shfl_xor(v, 8));
        const float mn = fmaxf(mrun[r], v);
        const float sf = __builtin_amdgcn_exp2f(mrun[r] - mn);
        mrun[r] = mn;
        float rs = 0.f;
#pragma unroll
        for (int n = 0; n < 4; ++n) {
          const float pv = __builtin_amdgcn_exp2f(sc[n][r] - mn);
          sc[n][r] = pv;
          rs += pv;
        }
        rs += __shfl_xor(rs, 1);
        rs += __shfl_xor(rs, 2);
        rs += __shfl_xor(rs, 4);
        rs += __shfl_xor(rs, 8);
        lrun[r] = lrun[r] * sf + rs;
#pragma unroll
        for (int nh = 0; nh < 8; ++nh) o[nh][r] *= sf;
      }
#pragma unroll
      for (int n = 0; n < 4; ++n)
#pragma unroll
        for (int r = 0; r < 4; ++r)
          lPw[(lg * 4 + r) * 72 + n * 16 + lr] = f2bf(sc[n][r]);

#pragma unroll
      for (int kc2 = 0; kc2 < 2; ++kc2) {
        bf16x8 pa = *(const bf16x8*)&lPw[lr * 72 + kc2 * 32 + lg * 8];
#pragma unroll
        for (int nh = 0; nh < 8; ++nh) {
          const int row = nh * 16 + lr;
          const int us = (kc2 * 4 + lg) ^ (row & 7);
          bf16x8 bv = *(const bf16x8*)&lVc[row * 64 + us * 8];
          o[nh] = __builtin_amdgcn_mfma_f32_16x16x32_bf16(pa, bv, o[nh], 0, 0, 0);
        }
      }
      __syncthreads();
      cur ^= 1;
    }

#pragma unroll
    for (int nh = 0; nh < 8; ++nh)
#pragma unroll
      for (int r = 0; r < 4; ++r) {
        const float val = o[nh][r] / lrun[r];
        ao[(size_t)(q0 + lg * 4 + r) * EQ + h * HDIM + nh * 16 + lr] = f2bf(val);
      }
  }
}

// ---------------------------------------------------------------- launch
extern "C" void kernel_launch(void* const* d_in, const int* in_sizes, int n_in,
                              void* d_out, int out_size, void* d_ws, size_t ws_size,
                              hipStream_t stream) {
  (void)in_sizes; (void)n_in; (void)out_size; (void)ws_size;
  const float* x    = (const float*)d_in[0];
  const float* wq   = (const float*)d_in[1];
  const float* wk   = (const float*)d_in[2];
  const float* wv   = (const float*)d_in[3];
  const float* wo   = (const float*)d_in[4];
  const float* cosb = (const float*)d_in[7];
  const float* sinb = (const float*)d_in[8];
  const int*   sidx = (const int*)d_in[10];
  float* out = (float*)d_out;

  // workspace layout; wqb/wkb/wvb are contiguous so B_qkv = [wq;wk;wv]
  u16* ws  = (u16*)d_ws;
  u16* xb  = ws;                                  // 2048*4096
  u16* wqb = xb  + (size_t)S_LEN * DM;            // 4096*4096
  u16* wkb = wqb + (size_t)EQ * DM;               // 1024*4096
  u16* wvb = wkb + (size_t)EKV * DM;              // 1024*4096
  u16* wob = wvb + (size_t)EKV * DM;              // 4096*4096
  u16* qb  = wob + (size_t)DM * EQ;               // 2048*4096
  u16* kb  = qb  + (size_t)S_LEN * EQ;            // 2048*1024
  u16* vb  = kb  + (size_t)S_LEN * EKV;           // 2048*1024
  u16* vtb = vb  + (size_t)S_LEN * EKV;           // 1024*2048
  u16* aob = vtb + (size_t)S_LEN * EKV;           // 2048*4096

  cast_all<<<2048, 256, 0, stream>>>(x, wq, wk, wv, wo, xb, wqb, wkb, wvb, wob);
  // fused QKV projection: B = [wq;wk;wv] (6144 x 4096); 1D grid 512, XCD-swizzled
  gemm2p<3, true><<<512, 256, 0, stream>>>(xb, wqb, qb, kb, vb, DM);
  rope_all<<<5120, 256, 0, stream>>>(qb, kb, cosb, sinb, sidx);
  transpose_v<<<dim3(EKV / 32, S_LEN / 32), dim3(32, 8), 0, stream>>>(vb, vtb);
  attn_fwd<<<dim3(16, NH), 256, 0, stream>>>(qb, kb, vtb, aob);
  // O projection: 1D grid 512, XCD-swizzled
  gemm2p<2, false><<<512, 256, 0, stream>>>(aob, wob, out, nullptr, nullptr, EQ);
}

// Round 14
// 319.404 us; speedup vs baseline: 1.2138x; 1.0068x over previous
//
#include <hip/hip_runtime.h>
#include <cstdint>
#include <cstddef>

#define S_LEN 2048
#define DM    4096
#define NH    32
#define NKV   8
#define HDIM  128
#define EQ    4096   // NH*HDIM
#define EKV   1024   // NKV*HDIM
#define SC_LOG2E 0.1275325477889277f   // (1/sqrt(128)) * log2(e)

typedef unsigned short u16;
typedef short bf16x8 __attribute__((ext_vector_type(8)));
typedef float f32x4  __attribute__((ext_vector_type(4)));

__device__ __forceinline__ u16 f2bf(float f) {
  union { float f; unsigned u; } v; v.f = f;
  unsigned r = v.u + 0x7FFFu + ((v.u >> 16) & 1u);
  return (u16)(r >> 16);
}
__device__ __forceinline__ float bf2f(u16 b) {
  union { unsigned u; float f; } v; v.u = ((unsigned)b) << 16;
  return v.f;
}
__device__ __forceinline__ void glds16(const void* g, void* l) {
  __builtin_amdgcn_global_load_lds((const __attribute__((address_space(1))) void*)g,
                                   (__attribute__((address_space(3))) void*)l, 16, 0, 0);
}

// ---------------------------------------------------------------- cast fp32->bf16
__global__ void cast_all(const float* __restrict__ x, const float* __restrict__ wq,
                         const float* __restrict__ wk, const float* __restrict__ wv,
                         const float* __restrict__ wo,
                         u16* __restrict__ xb, u16* __restrict__ wqb,
                         u16* __restrict__ wkb, u16* __restrict__ wvb,
                         u16* __restrict__ wob) {
  const size_t stride = (size_t)gridDim.x * blockDim.x;
  for (size_t u = (size_t)blockIdx.x * blockDim.x + threadIdx.x; u < 12582912u; u += stride) {
    const float* in; u16* outp; size_t i;
    if (u < 2097152u)      { in = x;  outp = xb;  i = u; }
    else if (u < 6291456u) { in = wq; outp = wqb; i = u - 2097152u; }
    else if (u < 7340032u) { in = wk; outp = wkb; i = u - 6291456u; }
    else if (u < 8388608u) { in = wv; outp = wvb; i = u - 7340032u; }
    else                   { in = wo; outp = wob; i = u - 8388608u; }
    float4 f = ((const float4*)in)[i];
    ushort4 b;
    b.x = f2bf(f.x); b.y = f2bf(f.y); b.z = f2bf(f.z); b.w = f2bf(f.w);
    ((ushort4*)outp)[i] = b;
  }
}

// ---------------------------------------------------------------- 2-phase GEMM, BM=128, BN=64*NF
// (R13 form, measured: QKV ~104.5us MfmaUtil 44%, 0 conflicts. XCD swizzle kept
// — measured time-neutral. Six structural alternates all landed 27-38%; the
// 2-phase's stage-drain + LDS/MFMA parity is the wall at this wave geometry.)
template<int UN>
__device__ __forceinline__ void stage_t(const u16* __restrict__ g, int ldg, int k0,
                                        u16* ldsp, int t) {
  const int wb = t & ~63;
#pragma unroll
  for (int j = 0; j < UN / 256; ++j) {
    const int U = j * 256 + t;
    const int row = U >> 3, u = U & 7;
    const int uu = u ^ (row & 7);
    glds16(g + (size_t)row * ldg + k0 + uu * 8, ldsp + (size_t)(j * 256 + wb) * 8);
  }
}

template<int NF, bool QKV3>
__global__ __launch_bounds__(256, 2)
void gemm2p(const u16* __restrict__ A, const u16* __restrict__ B,
            void* __restrict__ Cq, u16* __restrict__ Ck, u16* __restrict__ Cv,
            int K) {
  constexpr int BN = 64 * NF;
  constexpr int AT = 128 * 64;        // u16 per A tile (8192)
  constexpr int BT = BN * 64;         // u16 per B tile
  __shared__ u16 lds[2 * (AT + BT)];  // A0 @0, A1 @AT, B0 @2*AT, B1 @2*AT+BT
  const int t = threadIdx.x;
  const int l = t & 63, lr = l & 15, lg = l >> 4;
  const int wid = t >> 6, wm = wid >> 1, wn = wid & 1;

  const int bid = blockIdx.x;
  const int xcd = bid & 7, j = bid >> 3;
  const int bx = xcd * 4 + (j >> 4);
  const int by = j & 15;
  const int m0 = by * 128, n0 = bx * BN;
  const int KT = K >> 6;

  const u16* Ab = A + (size_t)m0 * K;
  const u16* Bb = B + (size_t)n0 * K;

  f32x4 acc[4][2 * NF] = {};

  stage_t<1024>(Ab, K, 0, &lds[0], t);
  stage_t<BT / 8>(Bb, K, 0, &lds[2 * AT], t);
  __syncthreads();

  int cur = 0;
#pragma unroll 1
  for (int tau = 0; tau < KT; ++tau) {
    const int kn = (tau + 1 < KT ? tau + 1 : KT - 1) * 64;
    stage_t<1024>(Ab, K, kn, &lds[(cur ^ 1) * AT], t);
    stage_t<BT / 8>(Bb, K, kn, &lds[2 * AT + (cur ^ 1) * BT], t);

    const int aBase = cur * AT;
    const int bBase = 2 * AT + cur * BT;

    bf16x8 af[4][2];
#pragma unroll
    for (int mf = 0; mf < 4; ++mf)
#pragma unroll
      for (int kk = 0; kk < 2; ++kk) {
        const int row = wm * 64 + mf * 16 + lr;
        const int uu = ((kk * 4 + lg) ^ (row & 7)) * 8;
        af[mf][kk] = *(const bf16x8*)&lds[aBase + row * 64 + uu];
      }

#pragma unroll
    for (int n = 0; n < 2 * NF; ++n) {
      const int brow = wn * (32 * NF) + n * 16 + lr;
      const int u0 = ((0 * 4 + lg) ^ (brow & 7)) * 8;
      const int u1 = ((1 * 4 + lg) ^ (brow & 7)) * 8;
      bf16x8 b0 = *(const bf16x8*)&lds[bBase + brow * 64 + u0];
      bf16x8 b1 = *(const bf16x8*)&lds[bBase + brow * 64 + u1];
#pragma unroll
      for (int mf = 0; mf < 4; ++mf) {
        acc[mf][n] = __builtin_amdgcn_mfma_f32_16x16x32_bf16(af[mf][0], b0, acc[mf][n], 0, 0, 0);
        acc[mf][n] = __builtin_amdgcn_mfma_f32_16x16x32_bf16(af[mf][1], b1, acc[mf][n], 0, 0, 0);
      }
    }
    __syncthreads();
    cur ^= 1;
  }

  // epilogue; fragment cols are 16-aligned so QKV routing is per-fragment
#pragma unroll
  for (int mf = 0; mf < 4; ++mf) {
    const int row = m0 + wm * 64 + mf * 16 + lg * 4;
#pragma unroll
    for (int n = 0; n < 2 * NF; ++n) {
      const int gc = n0 + wn * (32 * NF) + n * 16 + lr;
#pragma unroll
      for (int r = 0; r < 4; ++r) {
        if constexpr (QKV3) {
          if (gc < 4096)
            ((u16*)Cq)[(size_t)(row + r) * 4096 + gc] = f2bf(acc[mf][n][r]);
          else if (gc < 5120)
            Ck[(size_t)(row + r) * 1024 + (gc - 4096)] = f2bf(acc[mf][n][r]);
          else
            Cv[(size_t)(row + r) * 1024 + (gc - 5120)] = f2bf(acc[mf][n][r]);
        } else {
          ((float*)Cq)[(size_t)(row + r) * 4096 + gc] = acc[mf][n][r];
        }
      }
    }
  }
}

// ---------------------------------------------------------------- fused RoPE + V-transpose
// One dispatch, blockIdx ranges: [0,5120) = rope on q (1048576 units) and k
// (262144 units); [5120,7168) = 32x32 transpose tiles of v -> vt.
__global__ void rope_tr(u16* __restrict__ qd, u16* __restrict__ kd,
                        const float* __restrict__ cosb, const float* __restrict__ sinb,
                        const int* __restrict__ sidx,
                        const u16* __restrict__ v, u16* __restrict__ vt) {
  const int bid = blockIdx.x, t = threadIdx.x;
  if (bid < 5120) {
    const int u = bid * 256 + t;
    u16* base; int s, b;
    if (u < 1048576) {
      base = qd + (size_t)u * 8;
      s = u >> 9;
      b = u & 15;
    } else {
      const int u2 = u - 1048576;
      base = kd + (size_t)u2 * 8;
      s = u2 >> 7;
      b = u2 & 15;
    }
    const int pos = sidx[s];
    const float4 c  = *(const float4*)&cosb[pos * 64 + b * 4];
    const float4 sn = *(const float4*)&sinb[pos * 64 + b * 4];
    uint4 raw = *(uint4*)base;
    u16* pe = (u16*)&raw;
    const float cc[4] = {c.x, c.y, c.z, c.w};
    const float ss[4] = {sn.x, sn.y, sn.z, sn.w};
#pragma unroll
    for (int j = 0; j < 4; ++j) {
      const float xr = bf2f(pe[2 * j]), xi = bf2f(pe[2 * j + 1]);
      pe[2 * j]     = f2bf(xr * cc[j] - xi * ss[j]);
      pe[2 * j + 1] = f2bf(xr * ss[j] + xi * cc[j]);
    }
    *(uint4*)base = raw;
  } else {
    __shared__ u16 tile[32][33];
    const int tb = bid - 5120;
    const int c0 = (tb & 31) * 32, s0 = (tb >> 5) * 32;
    const int tx = t & 31, ty = t >> 5;   // 32 x 8
#pragma unroll
    for (int j = 0; j < 32; j += 8)
      tile[ty + j][tx] = v[(size_t)(s0 + ty + j) * EKV + c0 + tx];
    __syncthreads();
#pragma unroll
    for (int j = 0; j < 32; j += 8)
      vt[(size_t)(c0 + ty + j) * S_LEN + s0 + tx] = tile[tx][ty + j];
  }
}

// ---------------------------------------------------------------- flash attention
// Split causal pairing (block (p,h): sweep q-tile p then 31-p; 33 balanced
// tile-steps). SINGLE-buffered K/V: 41.6 KB LDS -> 3 blocks/CU = 12 waves/CU
// (was dbuf 73 KB -> 2 blocks). Trades intra-block prefetch overlap for +50%
// TLP; blocks desync naturally (different nt per p) so one block's stage
// drain is covered by the other two blocks' compute (m114 regime).
#define ATTN_STAGE(TK) { \
  const int kv0s = (TK) * 64; \
  _Pragma("unroll") \
  for (int hh = 0; hh < 4; ++hh) { \
    const int f = hh * 256 + t; \
    { const int row = f >> 4, uu = f & 15, us = uu ^ (row & 7); \
      glds16(&k[(size_t)(kv0s + row) * EKV + kvh * HDIM + us * 8], &lK[(hh * 256 + wb) * 8]); } \
    { const int row = f >> 3, uu = f & 7, us = uu ^ (row & 7); \
      glds16(&vt[(size_t)(kvh * HDIM + row) * S_LEN + kv0s + us * 8], &lV[(hh * 256 + wb) * 8]); } \
  } }

__global__ __launch_bounds__(256, 3)
void attn_fwd(const u16* __restrict__ q, const u16* __restrict__ k,
              const u16* __restrict__ vt, u16* __restrict__ ao) {
  __shared__ u16 lK[64 * 128];
  __shared__ u16 lV[128 * 64];
  __shared__ u16 lP[4 * 16 * 72];
  const int t = threadIdx.x, w = t >> 6, l = t & 63;
  const int lr = l & 15, lg = l >> 4;
  const int wb = t & ~63;
  const int p = blockIdx.x, h = blockIdx.y;
  const int kvh = h >> 2;
  u16* lPw = &lP[w * (16 * 72)];

#pragma unroll 1
  for (int ph = 0; ph < 2; ++ph) {
    const int qt = ph ? (31 - p) : p;
    const int q0 = qt * 64 + w * 16;
    const int nt = qt + 1;

    bf16x8 qa[4];
#pragma unroll
    for (int kc = 0; kc < 4; ++kc)
      qa[kc] = *(const bf16x8*)&q[(size_t)(q0 + lr) * EQ + h * HDIM + kc * 32 + lg * 8];

    f32x4 o[8] = {};
    float mrun[4], lrun[4];
#pragma unroll
    for (int r = 0; r < 4; ++r) { mrun[r] = -1e30f; lrun[r] = 0.f; }

#pragma unroll 1
    for (int tk = 0; tk < nt; ++tk) {
      const int kv0 = tk * 64;
      __syncthreads();                 // prior compute done reading LDS
      ATTN_STAGE(tk);
      __syncthreads();                 // stage drained (vmcnt(0) implicit)

      f32x4 sc[4] = {};
#pragma unroll
      for (int n = 0; n < 4; ++n) {
#pragma unroll
        for (int kc = 0; kc < 4; ++kc) {
          const int row = n * 16 + lr;
          const int us = (kc * 4 + lg) ^ (row & 7);
          bf16x8 bk = *(const bf16x8*)&lK[row * 128 + us * 8];
          sc[n] = __builtin_amdgcn_mfma_f32_16x16x32_bf16(qa[kc], bk, sc[n], 0, 0, 0);
        }
      }

#pragma unroll
      for (int n = 0; n < 4; ++n) {
        const int kvc = kv0 + n * 16 + lr;
#pragma unroll
        for (int r = 0; r < 4; ++r) {
          const int qr = q0 + lg * 4 + r;
          const float v = sc[n][r] * SC_LOG2E;
          sc[n][r] = (kvc > qr) ? -1e30f : v;
        }
      }
#pragma unroll
      for (int r = 0; r < 4; ++r) {
        float v = fmaxf(fmaxf(sc[0][r], sc[1][r]), fmaxf(sc[2][r], sc[3][r]));
        v = fmaxf(v, __shfl_xor(v, 1));
        v = fmaxf(v, __shfl_xor(v, 2));
        v = fmaxf(v, __shfl_xor(v, 4));
        v = fmaxf(v, __shfl_xor(v, 8));
        const float mn = fmaxf(mrun[r], v);
        const float sf = __builtin_amdgcn_exp2f(mrun[r] - mn);
        mrun[r] = mn;
        float rs = 0.f;
#pragma unroll
        for (int n = 0; n < 4; ++n) {
          const float pv = __builtin_amdgcn_exp2f(sc[n][r] - mn);
          sc[n][r] = pv;
          rs += pv;
        }
        rs += __shfl_xor(rs, 1);
        rs += __shfl_xor(rs, 2);
        rs += __shfl_xor(rs, 4);
        rs += __shfl_xor(rs, 8);
        lrun[r] = lrun[r] * sf + rs;
#pragma unroll
        for (int nh = 0; nh < 8; ++nh) o[nh][r] *= sf;
      }
#pragma unroll
      for (int n = 0; n < 4; ++n)
#pragma unroll
        for (int r = 0; r < 4; ++r)
          lPw[(lg * 4 + r) * 72 + n * 16 + lr] = f2bf(sc[n][r]);

#pragma unroll
      for (int kc2 = 0; kc2 < 2; ++kc2) {
        bf16x8 pa = *(const bf16x8*)&lPw[lr * 72 + kc2 * 32 + lg * 8];
#pragma unroll
        for (int nh = 0; nh < 8; ++nh) {
          const int row = nh * 16 + lr;
          const int us = (kc2 * 4 + lg) ^ (row & 7);
          bf16x8 bv = *(const bf16x8*)&lV[row * 64 + us * 8];
          o[nh] = __builtin_amdgcn_mfma_f32_16x16x32_bf16(pa, bv, o[nh], 0, 0, 0);
        }
      }
    }

#pragma unroll
    for (int nh = 0; nh < 8; ++nh)
#pragma unroll
      for (int r = 0; r < 4; ++r) {
        const float val = o[nh][r] / lrun[r];
        ao[(size_t)(q0 + lg * 4 + r) * EQ + h * HDIM + nh * 16 + lr] = f2bf(val);
      }
  }
}

// ---------------------------------------------------------------- launch
extern "C" void kernel_launch(void* const* d_in, const int* in_sizes, int n_in,
                              void* d_out, int out_size, void* d_ws, size_t ws_size,
                              hipStream_t stream) {
  (void)in_sizes; (void)n_in; (void)out_size; (void)ws_size;
  const float* x    = (const float*)d_in[0];
  const float* wq   = (const float*)d_in[1];
  const float* wk   = (const float*)d_in[2];
  const float* wv   = (const float*)d_in[3];
  const float* wo   = (const float*)d_in[4];
  const float* cosb = (const float*)d_in[7];
  const float* sinb = (const float*)d_in[8];
  const int*   sidx = (const int*)d_in[10];
  float* out = (float*)d_out;

  // workspace layout; wqb/wkb/wvb are contiguous so B_qkv = [wq;wk;wv]
  u16* ws  = (u16*)d_ws;
  u16* xb  = ws;                                  // 2048*4096
  u16* wqb = xb  + (size_t)S_LEN * DM;            // 4096*4096
  u16* wkb = wqb + (size_t)EQ * DM;               // 1024*4096
  u16* wvb = wkb + (size_t)EKV * DM;              // 1024*4096
  u16* wob = wvb + (size_t)EKV * DM;              // 4096*4096
  u16* qb  = wob + (size_t)DM * EQ;               // 2048*4096
  u16* kb  = qb  + (size_t)S_LEN * EQ;            // 2048*1024
  u16* vb  = kb  + (size_t)S_LEN * EKV;           // 2048*1024
  u16* vtb = vb  + (size_t)S_LEN * EKV;           // 1024*2048
  u16* aob = vtb + (size_t)S_LEN * EKV;           // 2048*4096

  cast_all<<<2048, 256, 0, stream>>>(x, wq, wk, wv, wo, xb, wqb, wkb, wvb, wob);
  // fused QKV projection: B = [wq;wk;wv] (6144 x 4096); 1D grid 512, XCD-swizzled
  gemm2p<3, true><<<512, 256, 0, stream>>>(xb, wqb, qb, kb, vb, DM);
  // fused RoPE(q,k) + V-transpose: one dispatch, 5120 + 2048 blocks
  rope_tr<<<7168, 256, 0, stream>>>(qb, kb, cosb, sinb, sidx, vb, vtb);
  attn_fwd<<<dim3(16, NH), 256, 0, stream>>>(qb, kb, vtb, aob);
  // O projection: 1D grid 512, XCD-swizzled
  gemm2p<2, false><<<512, 256, 0, stream>>>(aob, wob, out, nullptr, nullptr, EQ);
}

// Round 15
// 299.445 us; speedup vs baseline: 1.2947x; 1.0667x over previous
//
#include <hip/hip_runtime.h>
#include <cstdint>
#include <cstddef>

#define S_LEN 2048
#define DM    4096
#define NH    32
#define NKV   8
#define HDIM  128
#define EQ    4096   // NH*HDIM
#define EKV   1024   // NKV*HDIM
#define SC_LOG2E 0.1275325477889277f   // (1/sqrt(128)) * log2(e)

typedef unsigned short u16;
typedef short bf16x8 __attribute__((ext_vector_type(8)));
typedef float f32x4  __attribute__((ext_vector_type(4)));

__device__ __forceinline__ u16 f2bf(float f) {
  union { float f; unsigned u; } v; v.f = f;
  unsigned r = v.u + 0x7FFFu + ((v.u >> 16) & 1u);
  return (u16)(r >> 16);
}
__device__ __forceinline__ float bf2f(u16 b) {
  union { unsigned u; float f; } v; v.u = ((unsigned)b) << 16;
  return v.f;
}
// HW packed fp32->bf16 RNE (ties-even, same as f2bf); a -> low 16, b -> high 16
__device__ __forceinline__ unsigned cvt2bf(float a, float b) {
  unsigned r;
  asm("v_cvt_pk_bf16_f32 %0, %1, %2" : "=v"(r) : "v"(a), "v"(b));
  return r;
}
__device__ __forceinline__ void glds16(const void* g, void* l) {
  __builtin_amdgcn_global_load_lds((const __attribute__((address_space(1))) void*)g,
                                   (__attribute__((address_space(3))) void*)l, 16, 0, 0);
}

// ---------------------------------------------------------------- cast fp32->bf16
__global__ void cast_all(const float* __restrict__ x, const float* __restrict__ wq,
                         const float* __restrict__ wk, const float* __restrict__ wv,
                         const float* __restrict__ wo,
                         u16* __restrict__ xb, u16* __restrict__ wqb,
                         u16* __restrict__ wkb, u16* __restrict__ wvb,
                         u16* __restrict__ wob) {
  const size_t stride = (size_t)gridDim.x * blockDim.x;
  for (size_t u = (size_t)blockIdx.x * blockDim.x + threadIdx.x; u < 12582912u; u += stride) {
    const float* in; u16* outp; size_t i;
    if (u < 2097152u)      { in = x;  outp = xb;  i = u; }
    else if (u < 6291456u) { in = wq; outp = wqb; i = u - 2097152u; }
    else if (u < 7340032u) { in = wk; outp = wkb; i = u - 6291456u; }
    else if (u < 8388608u) { in = wv; outp = wvb; i = u - 7340032u; }
    else                   { in = wo; outp = wob; i = u - 8388608u; }
    float4 f = ((const float4*)in)[i];
    ushort4 b;
    b.x = f2bf(f.x); b.y = f2bf(f.y); b.z = f2bf(f.z); b.w = f2bf(f.w);
    ((ushort4*)outp)[i] = b;
  }
}

// ---------------------------------------------------------------- 2-phase GEMM, BM=128, BN=64*NF
// (R13 form, measured: QKV ~104.5us MfmaUtil 44%, 0 conflicts. XCD swizzle kept
// — measured time-neutral.)
template<int UN>
__device__ __forceinline__ void stage_t(const u16* __restrict__ g, int ldg, int k0,
                                        u16* ldsp, int t) {
  const int wb = t & ~63;
#pragma unroll
  for (int j = 0; j < UN / 256; ++j) {
    const int U = j * 256 + t;
    const int row = U >> 3, u = U & 7;
    const int uu = u ^ (row & 7);
    glds16(g + (size_t)row * ldg + k0 + uu * 8, ldsp + (size_t)(j * 256 + wb) * 8);
  }
}

template<int NF, bool QKV3>
__global__ __launch_bounds__(256, 2)
void gemm2p(const u16* __restrict__ A, const u16* __restrict__ B,
            void* __restrict__ Cq, u16* __restrict__ Ck, u16* __restrict__ Cv,
            int K) {
  constexpr int BN = 64 * NF;
  constexpr int AT = 128 * 64;        // u16 per A tile (8192)
  constexpr int BT = BN * 64;         // u16 per B tile
  __shared__ u16 lds[2 * (AT + BT)];  // A0 @0, A1 @AT, B0 @2*AT, B1 @2*AT+BT
  const int t = threadIdx.x;
  const int l = t & 63, lr = l & 15, lg = l >> 4;
  const int wid = t >> 6, wm = wid >> 1, wn = wid & 1;

  const int bid = blockIdx.x;
  const int xcd = bid & 7, j = bid >> 3;
  const int bx = xcd * 4 + (j >> 4);
  const int by = j & 15;
  const int m0 = by * 128, n0 = bx * BN;
  const int KT = K >> 6;

  const u16* Ab = A + (size_t)m0 * K;
  const u16* Bb = B + (size_t)n0 * K;

  f32x4 acc[4][2 * NF] = {};

  stage_t<1024>(Ab, K, 0, &lds[0], t);
  stage_t<BT / 8>(Bb, K, 0, &lds[2 * AT], t);
  __syncthreads();

  int cur = 0;
#pragma unroll 1
  for (int tau = 0; tau < KT; ++tau) {
    const int kn = (tau + 1 < KT ? tau + 1 : KT - 1) * 64;
    stage_t<1024>(Ab, K, kn, &lds[(cur ^ 1) * AT], t);
    stage_t<BT / 8>(Bb, K, kn, &lds[2 * AT + (cur ^ 1) * BT], t);

    const int aBase = cur * AT;
    const int bBase = 2 * AT + cur * BT;

    bf16x8 af[4][2];
#pragma unroll
    for (int mf = 0; mf < 4; ++mf)
#pragma unroll
      for (int kk = 0; kk < 2; ++kk) {
        const int row = wm * 64 + mf * 16 + lr;
        const int uu = ((kk * 4 + lg) ^ (row & 7)) * 8;
        af[mf][kk] = *(const bf16x8*)&lds[aBase + row * 64 + uu];
      }

#pragma unroll
    for (int n = 0; n < 2 * NF; ++n) {
      const int brow = wn * (32 * NF) + n * 16 + lr;
      const int u0 = ((0 * 4 + lg) ^ (brow & 7)) * 8;
      const int u1 = ((1 * 4 + lg) ^ (brow & 7)) * 8;
      bf16x8 b0 = *(const bf16x8*)&lds[bBase + brow * 64 + u0];
      bf16x8 b1 = *(const bf16x8*)&lds[bBase + brow * 64 + u1];
#pragma unroll
      for (int mf = 0; mf < 4; ++mf) {
        acc[mf][n] = __builtin_amdgcn_mfma_f32_16x16x32_bf16(af[mf][0], b0, acc[mf][n], 0, 0, 0);
        acc[mf][n] = __builtin_amdgcn_mfma_f32_16x16x32_bf16(af[mf][1], b1, acc[mf][n], 0, 0, 0);
      }
    }
    __syncthreads();
    cur ^= 1;
  }

  // epilogue; fragment cols are 16-aligned so QKV routing is per-fragment
#pragma unroll
  for (int mf = 0; mf < 4; ++mf) {
    const int row = m0 + wm * 64 + mf * 16 + lg * 4;
#pragma unroll
    for (int n = 0; n < 2 * NF; ++n) {
      const int gc = n0 + wn * (32 * NF) + n * 16 + lr;
#pragma unroll
      for (int r = 0; r < 4; ++r) {
        if constexpr (QKV3) {
          if (gc < 4096)
            ((u16*)Cq)[(size_t)(row + r) * 4096 + gc] = f2bf(acc[mf][n][r]);
          else if (gc < 5120)
            Ck[(size_t)(row + r) * 1024 + (gc - 4096)] = f2bf(acc[mf][n][r]);
          else
            Cv[(size_t)(row + r) * 1024 + (gc - 5120)] = f2bf(acc[mf][n][r]);
        } else {
          ((float*)Cq)[(size_t)(row + r) * 4096 + gc] = acc[mf][n][r];
        }
      }
    }
  }
}

// ---------------------------------------------------------------- fused RoPE + V-transpose
__global__ void rope_tr(u16* __restrict__ qd, u16* __restrict__ kd,
                        const float* __restrict__ cosb, const float* __restrict__ sinb,
                        const int* __restrict__ sidx,
                        const u16* __restrict__ v, u16* __restrict__ vt) {
  const int bid = blockIdx.x, t = threadIdx.x;
  if (bid < 5120) {
    const int u = bid * 256 + t;
    u16* base; int s, b;
    if (u < 1048576) {
      base = qd + (size_t)u * 8;
      s = u >> 9;
      b = u & 15;
    } else {
      const int u2 = u - 1048576;
      base = kd + (size_t)u2 * 8;
      s = u2 >> 7;
      b = u2 & 15;
    }
    const int pos = sidx[s];
    const float4 c  = *(const float4*)&cosb[pos * 64 + b * 4];
    const float4 sn = *(const float4*)&sinb[pos * 64 + b * 4];
    uint4 raw = *(uint4*)base;
    u16* pe = (u16*)&raw;
    const float cc[4] = {c.x, c.y, c.z, c.w};
    const float ss[4] = {sn.x, sn.y, sn.z, sn.w};
#pragma unroll
    for (int j = 0; j < 4; ++j) {
      const float xr = bf2f(pe[2 * j]), xi = bf2f(pe[2 * j + 1]);
      pe[2 * j]     = f2bf(xr * cc[j] - xi * ss[j]);
      pe[2 * j + 1] = f2bf(xr * ss[j] + xi * cc[j]);
    }
    *(uint4*)base = raw;
  } else {
    __shared__ u16 tile[32][33];
    const int tb = bid - 5120;
    const int c0 = (tb & 31) * 32, s0 = (tb >> 5) * 32;
    const int tx = t & 31, ty = t >> 5;   // 32 x 8
#pragma unroll
    for (int j = 0; j < 32; j += 8)
      tile[ty + j][tx] = v[(size_t)(s0 + ty + j) * EKV + c0 + tx];
    __syncthreads();
#pragma unroll
    for (int j = 0; j < 32; j += 8)
      vt[(size_t)(c0 + ty + j) * S_LEN + s0 + tx] = tile[tx][ty + j];
  }
}

// ---------------------------------------------------------------- flash attention
// Split causal pairing (block (p,h): q-tile p then 31-p; 33 balanced steps),
// single-buffered K/V (41.6 KB -> 3 blocks/CU). NEW: swapped QK^T on the
// SPLIT structure — mfma(K, Q) puts q = lane&15: each lane owns one q-row's
// 16 scores (kv = n*16 + lg*4 + r). Softmax: in-register reduce + 2 shfl_xor
// (vs 32 shfl), P via cvt_pk + 4 ds_write_b64 (vs 16 scalar writes). R10
// proved numerics; its regression was MERGED-state spill (192MB WRITE_SIZE) —
// split state (~90 VGPR) fits. PV loop and K-frag reads unchanged.
#define ATTN_STAGE(TK) { \
  const int kv0s = (TK) * 64; \
  _Pragma("unroll") \
  for (int hh = 0; hh < 4; ++hh) { \
    const int f = hh * 256 + t; \
    { const int row = f >> 4, uu = f & 15, us = uu ^ (row & 7); \
      glds16(&k[(size_t)(kv0s + row) * EKV + kvh * HDIM + us * 8], &lK[(hh * 256 + wb) * 8]); } \
    { const int row = f >> 3, uu = f & 7, us = uu ^ (row & 7); \
      glds16(&vt[(size_t)(kvh * HDIM + row) * S_LEN + kv0s + us * 8], &lV[(hh * 256 + wb) * 8]); } \
  } }

__global__ __launch_bounds__(256, 3)
void attn_fwd(const u16* __restrict__ q, const u16* __restrict__ k,
              const u16* __restrict__ vt, u16* __restrict__ ao) {
  __shared__ u16 lK[64 * 128];
  __shared__ u16 lV[128 * 64];
  __shared__ u16 lP[4 * 16 * 72];
  const int t = threadIdx.x, w = t >> 6, l = t & 63;
  const int lr = l & 15, lg = l >> 4;
  const int wb = t & ~63;
  const int p = blockIdx.x, h = blockIdx.y;
  const int kvh = h >> 2;
  u16* lPw = &lP[w * (16 * 72)];

#pragma unroll 1
  for (int ph = 0; ph < 2; ++ph) {
    const int qt = ph ? (31 - p) : p;
    const int q0 = qt * 64 + w * 16;
    const int nt = qt + 1;

    bf16x8 qa[4];
#pragma unroll
    for (int kc = 0; kc < 4; ++kc)
      qa[kc] = *(const bf16x8*)&q[(size_t)(q0 + lr) * EQ + h * HDIM + kc * 32 + lg * 8];

    f32x4 o[8] = {};
    float mrun = -1e30f, lrun = 0.f;   // per-lane: q = q0 + lr

#pragma unroll 1
    for (int tk = 0; tk < nt; ++tk) {
      const int kv0 = tk * 64;
      __syncthreads();                 // prior compute done reading LDS
      ATTN_STAGE(tk);
      __syncthreads();                 // stage drained (vmcnt(0) implicit)

      // swapped QK^T: sc[n] has q = lr, kv = kv0 + n*16 + lg*4 + r
      f32x4 sc[4] = {};
#pragma unroll
      for (int n = 0; n < 4; ++n) {
#pragma unroll
        for (int kc = 0; kc < 4; ++kc) {
          const int row = n * 16 + lr;
          const int us = (kc * 4 + lg) ^ (row & 7);
          bf16x8 bk = *(const bf16x8*)&lK[row * 128 + us * 8];
          sc[n] = __builtin_amdgcn_mfma_f32_16x16x32_bf16(bk, qa[kc], sc[n], 0, 0, 0);
        }
      }

      // mask + scale (log2 domain)
      const int qr = q0 + lr;
#pragma unroll
      for (int n = 0; n < 4; ++n)
#pragma unroll
        for (int r = 0; r < 4; ++r) {
          const int kvc = kv0 + n * 16 + lg * 4 + r;
          const float vv = sc[n][r] * SC_LOG2E;
          sc[n][r] = (kvc > qr) ? -1e30f : vv;
        }

      // in-register row reduce (row = one q, spread over lanes lr, xor16/32)
      float vmx = sc[0][0];
#pragma unroll
      for (int n = 0; n < 4; ++n)
#pragma unroll
        for (int r = 0; r < 4; ++r) vmx = fmaxf(vmx, sc[n][r]);
      vmx = fmaxf(vmx, __shfl_xor(vmx, 16));
      vmx = fmaxf(vmx, __shfl_xor(vmx, 32));
      const float mn = fmaxf(mrun, vmx);
      const float sf = __builtin_amdgcn_exp2f(mrun - mn);
      mrun = mn;
      float rs = 0.f;
#pragma unroll
      for (int n = 0; n < 4; ++n)
#pragma unroll
        for (int r = 0; r < 4; ++r) {
          const float pv = __builtin_amdgcn_exp2f(sc[n][r] - mn);
          sc[n][r] = pv;
          rs += pv;
        }
      rs += __shfl_xor(rs, 16);
      rs += __shfl_xor(rs, 32);
      lrun = lrun * sf + rs;

      // o rescale: o[nh][r] sits at q = lg*4 + r -> fetch sf from lane lg*4+r
      {
        const float s0 = __shfl(sf, lg * 4 + 0);
        const float s1 = __shfl(sf, lg * 4 + 1);
        const float s2 = __shfl(sf, lg * 4 + 2);
        const float s3 = __shfl(sf, lg * 4 + 3);
#pragma unroll
        for (int nh = 0; nh < 8; ++nh) {
          o[nh][0] *= s0; o[nh][1] *= s1; o[nh][2] *= s2; o[nh][3] *= s3;
        }
      }

      // P -> LDS: lane's 4 kv-contiguous values per n -> cvt_pk + ds_write_b64
#pragma unroll
      for (int n = 0; n < 4; ++n) {
        uint2 wpk;
        wpk.x = cvt2bf(sc[n][0], sc[n][1]);
        wpk.y = cvt2bf(sc[n][2], sc[n][3]);
        *(uint2*)&lPw[lr * 72 + n * 16 + lg * 4] = wpk;
      }

      // PV (unchanged): pa has q = lr rows, kv-contiguous k
#pragma unroll
      for (int kc2 = 0; kc2 < 2; ++kc2) {
        bf16x8 pa = *(const bf16x8*)&lPw[lr * 72 + kc2 * 32 + lg * 8];
#pragma unroll
        for (int nh = 0; nh < 8; ++nh) {
          const int row = nh * 16 + lr;
          const int us = (kc2 * 4 + lg) ^ (row & 7);
          bf16x8 bv = *(const bf16x8*)&lV[row * 64 + us * 8];
          o[nh] = __builtin_amdgcn_mfma_f32_16x16x32_bf16(pa, bv, o[nh], 0, 0, 0);
        }
      }
    }

    // lrun lives at q=lr; outputs need q=lg*4+r
    {
      const float l0 = __shfl(lrun, lg * 4 + 0), l1 = __shfl(lrun, lg * 4 + 1);
      const float l2 = __shfl(lrun, lg * 4 + 2), l3 = __shfl(lrun, lg * 4 + 3);
      const float rl[4] = {l0, l1, l2, l3};
#pragma unroll
      for (int nh = 0; nh < 8; ++nh)
#pragma unroll
        for (int r = 0; r < 4; ++r) {
          const float val = o[nh][r] / rl[r];
          ao[(size_t)(q0 + lg * 4 + r) * EQ + h * HDIM + nh * 16 + lr] = f2bf(val);
        }
    }
  }
}

// ---------------------------------------------------------------- launch
extern "C" void kernel_launch(void* const* d_in, const int* in_sizes, int n_in,
                              void* d_out, int out_size, void* d_ws, size_t ws_size,
                              hipStream_t stream) {
  (void)in_sizes; (void)n_in; (void)out_size; (void)ws_size;
  const float* x    = (const float*)d_in[0];
  const float* wq   = (const float*)d_in[1];
  const float* wk   = (const float*)d_in[2];
  const float* wv   = (const float*)d_in[3];
  const float* wo   = (const float*)d_in[4];
  const float* cosb = (const float*)d_in[7];
  const float* sinb = (const float*)d_in[8];
  const int*   sidx = (const int*)d_in[10];
  float* out = (float*)d_out;

  // workspace layout; wqb/wkb/wvb are contiguous so B_qkv = [wq;wk;wv]
  u16* ws  = (u16*)d_ws;
  u16* xb  = ws;                                  // 2048*4096
  u16* wqb = xb  + (size_t)S_LEN * DM;            // 4096*4096
  u16* wkb = wqb + (size_t)EQ * DM;               // 1024*4096
  u16* wvb = wkb + (size_t)EKV * DM;              // 1024*4096
  u16* wob = wvb + (size_t)EKV * DM;              // 4096*4096
  u16* qb  = wob + (size_t)DM * EQ;               // 2048*4096
  u16* kb  = qb  + (size_t)S_LEN * EQ;            // 2048*1024
  u16* vb  = kb  + (size_t)S_LEN * EKV;           // 2048*1024
  u16* vtb = vb  + (size_t)S_LEN * EKV;           // 1024*2048
  u16* aob = vtb + (size_t)S_LEN * EKV;           // 2048*4096

  cast_all<<<2048, 256, 0, stream>>>(x, wq, wk, wv, wo, xb, wqb, wkb, wvb, wob);
  // fused QKV projection: B = [wq;wk;wv] (6144 x 4096); 1D grid 512, XCD-swizzled
  gemm2p<3, true><<<512, 256, 0, stream>>>(xb, wqb, qb, kb, vb, DM);
  // fused RoPE(q,k) + V-transpose: one dispatch, 5120 + 2048 blocks
  rope_tr<<<7168, 256, 0, stream>>>(qb, kb, cosb, sinb, sidx, vb, vtb);
  attn_fwd<<<dim3(16, NH), 256, 0, stream>>>(qb, kb, vtb, aob);
  // O projection: 1D grid 512, XCD-swizzled
  gemm2p<2, false><<<512, 256, 0, stream>>>(aob, wob, out, nullptr, nullptr, EQ);
}